// Round 4
// baseline (412.647 us; speedup 1.0000x reference)
//
#include <hip/hip_runtime.h>
#include <hip/hip_bf16.h>
#include <math.h>

#define N_PTS 16384
#define NUM_G 64
#define GRP_K 32
#define EPSF 1e-5f

typedef short bf16x8 __attribute__((ext_vector_type(8)));
typedef short bf16x4 __attribute__((ext_vector_type(4)));
typedef float f32x4 __attribute__((ext_vector_type(4)));
typedef unsigned short u16x8 __attribute__((ext_vector_type(8)));

__device__ __forceinline__ unsigned short f2bf(float x) {
    unsigned int u = __builtin_bit_cast(unsigned int, x);
    u = (u + 0x7FFFu + ((u >> 16) & 1u)) >> 16;
    return (unsigned short)u;
}
__device__ __forceinline__ float bf2f(unsigned short h) {
    unsigned int u = ((unsigned int)h) << 16;
    return __builtin_bit_cast(float, u);
}

// ---------------- Fused Phase A: FPS v5 (reverted — best measured 125.7us) + weight prep ----------------
// v6/v7 (hoist/pin) neutral, v8 (key-carried+MUX) regressed to 152us.
// Chip-wide VALUBusy 7.9% / 12.5% active-CU fraction => ~63% per-active-CU:
// the 32 FPS CUs are VALU-issue-bound on the scan; serial-argmax structure
// caps improvement. This is the structural floor for 32 blocks. Do not touch.
__global__ __launch_bounds__(1024)
__attribute__((amdgpu_waves_per_eu(4, 4)))
void fps_prep_kernel(const float* __restrict__ pcd, int* __restrict__ cidx,
                     const float* __restrict__ w2, const float* __restrict__ w3,
                     const float* __restrict__ w4,
                     unsigned short* __restrict__ w2t,
                     unsigned short* __restrict__ w3t,
                     unsigned short* __restrict__ w4t) {
    __shared__ unsigned long long wk[2][16];
    __shared__ int clds[NUM_G];
    __shared__ unsigned short tl[64][72];

    const int tid = threadIdx.x;

    if (blockIdx.x >= 32) {
        if (tid < 256) {
            const int tile = blockIdx.x - 32;
            const float* src;
            unsigned short* dst;
            int K, N, kt, nt;
            if (tile < 8) {
                src = w2; dst = w2t; K = 128; N = 256;
                kt = tile >> 2; nt = tile & 3;
            } else if (tile < 72) {
                int t2 = tile - 8;
                src = w3; dst = w3t; K = 512; N = 512;
                kt = t2 >> 3; nt = t2 & 7;
            } else {
                int t2 = tile - 72;
                src = w4; dst = w4t; K = 512; N = 384;
                kt = t2 / 6; nt = t2 % 6;
            }
            const int k0 = kt * 64, n0 = nt * 64;
            const int c = tid & 63, r0 = tid >> 6;
#pragma unroll
            for (int i = 0; i < 16; ++i) {
                int r = 4 * i + r0;
                tl[r][c] = f2bf(src[(size_t)(k0 + r) * N + n0 + c]);
            }
            __syncthreads();
            const int n = tid >> 2;
            const int kc = (tid & 3) * 16;
            u16x8 v0, v1;
#pragma unroll
            for (int j = 0; j < 8; ++j) {
                v0[j] = tl[kc + j][n];
                v1[j] = tl[kc + 8 + j][n];
            }
            *(u16x8*)(dst + (size_t)(n0 + n) * K + k0 + kc) = v0;
            *(u16x8*)(dst + (size_t)(n0 + n) * K + k0 + kc + 8) = v1;
        } else {
            __syncthreads();
        }
        return;
    }

    const int b = blockIdx.x;
    const int lane = tid & 63, w = tid >> 6;
    const float* xb = pcd + (size_t)b * 6 * N_PTS;
    const float4* Xc = (const float4*)xb;
    const float4* Yc = (const float4*)(xb + N_PTS);
    const float4* Zc = (const float4*)(xb + 2 * N_PTS);

    float dist[16];
#pragma unroll
    for (int j = 0; j < 16; ++j) dist[j] = 1e10f;

    int far = 0;
    for (int it = 0; it < NUM_G; ++it) {
        int fu = __builtin_amdgcn_readfirstlane(far);
        float cx = xb[fu], cy = xb[N_PTS + fu], cz = xb[2 * N_PTS + fu];
        if (tid == 0) clds[it] = fu;

        float bv = -1.0f;
        int bj = 0;
#pragma unroll
        for (int jp = 0; jp < 4; ++jp) {
            float4 xq = Xc[tid * 4 + jp];
            float4 yq = Yc[tid * 4 + jp];
            float4 zq = Zc[tid * 4 + jp];
            float xa[4] = {xq.x, xq.y, xq.z, xq.w};
            float ya[4] = {yq.x, yq.y, yq.z, yq.w};
            float za[4] = {zq.x, zq.y, zq.z, zq.w};
#pragma unroll
            for (int u = 0; u < 4; ++u) {
                const int j = jp * 4 + u;
                float dx = __fsub_rn(xa[u], cx);
                float dy = __fsub_rn(ya[u], cy);
                float dz = __fsub_rn(za[u], cz);
                float d = __fadd_rn(__fadd_rn(__fmul_rn(dx, dx), __fmul_rn(dy, dy)),
                                    __fmul_rn(dz, dz));
                dist[j] = fminf(dist[j], d);
                if (dist[j] > bv) { bv = dist[j]; bj = j; }
            }
        }
        float vmax = bv;
#pragma unroll
        for (int m = 1; m < 64; m <<= 1) {
            float o = __shfl_xor(vmax, m, 64);
            vmax = o > vmax ? o : vmax;
        }
        unsigned long long mk = __ballot(bv == vmax);
        int fl = __ffsll((unsigned long long)mk) - 1;
        int bjw = __shfl(bj, fl, 64);
        int idx = (((w << 6) | fl) << 4) + bjw;
        unsigned long long key =
            ((unsigned long long)__float_as_uint(vmax) << 32) | (unsigned int)~idx;
        if (lane == 0) wk[it & 1][w] = key;
        __syncthreads();
        unsigned long long k2 = (lane < 16) ? wk[it & 1][lane] : 0ull;
#pragma unroll
        for (int m = 1; m < 16; m <<= 1) {
            unsigned long long o = __shfl_xor(k2, m, 64);
            k2 = o > k2 ? o : k2;
        }
        k2 = __shfl(k2, 0, 64);
        far = (int)(~(unsigned int)k2);
    }
    __syncthreads();
    if (tid < NUM_G) cidx[b * NUM_G + tid] = clds[tid];
}

// ---------------- Phase B: KNN v3 — lazy top-4 cache, one wave per group (unchanged) ----------------
__device__ __forceinline__ void merge2(unsigned long long& a1, unsigned long long& a2,
                                       unsigned long long o1, unsigned long long o2) {
    unsigned long long hi = a1 > o1 ? a1 : o1;
    a1 = a1 < o1 ? a1 : o1;
    unsigned long long lo2 = a2 < o2 ? a2 : o2;
    a2 = hi < lo2 ? hi : lo2;
}
// sorted ascending insert of v into (c0<=c1<=c2<=c3), keeping 4 smallest
__device__ __forceinline__ void ins4(unsigned long long& c0, unsigned long long& c1,
                                     unsigned long long& c2, unsigned long long& c3,
                                     unsigned long long v) {
    if (v < c3) {
        unsigned long long t3 = c2 > v ? c2 : v;
        unsigned long long t2 = c2 > v ? v : c2;
        unsigned long long u2 = c1 > t2 ? c1 : t2;
        unsigned long long u1 = c1 > t2 ? t2 : c1;
        unsigned long long s1 = c0 > u1 ? c0 : u1;
        unsigned long long s0 = c0 > u1 ? u1 : c0;
        c0 = s0; c1 = s1; c2 = u2; c3 = t3;
    }
}

__global__ __launch_bounds__(64)
__attribute__((amdgpu_waves_per_eu(4, 4)))
void knn_kernel(const float* __restrict__ pcd,
                const int* __restrict__ cidx,
                float* __restrict__ xout) {
    const int b = blockIdx.x & 31;       // XCD-locality swizzle
    const int g = blockIdx.x >> 5;
    const int bg_out = b * NUM_G + g;
    const int lane = threadIdx.x;
    const float* xb = pcd + (size_t)b * 6 * N_PTS;

    const int ci = cidx[bg_out];
    const float cx = xb[ci], cy = xb[N_PTS + ci], cz = xb[2 * N_PTS + ci];

    const float4* X4 = (const float4*)xb;
    const float4* Y4 = (const float4*)(xb + N_PTS);
    const float4* Z4 = (const float4*)(xb + 2 * N_PTS);

    // per-lane sorted top-4 cache of its 256 points p = j*256 + lane*4 + u
    unsigned long long c0 = ~0ull, c1 = ~0ull, c2 = ~0ull, c3 = ~0ull;
#pragma unroll 8
    for (int j = 0; j < 64; ++j) {
        float4 xv = X4[j * 64 + lane];
        float4 yv = Y4[j * 64 + lane];
        float4 zv = Z4[j * 64 + lane];
        float xs4[4] = {xv.x, xv.y, xv.z, xv.w};
        float ys4[4] = {yv.x, yv.y, yv.z, yv.w};
        float zs4[4] = {zv.x, zv.y, zv.z, zv.w};
        unsigned int p = (unsigned int)(j * 256 + lane * 4);
#pragma unroll
        for (int u = 0; u < 4; ++u) {
            float dx = __fsub_rn(cx, xs4[u]);
            float dy = __fsub_rn(cy, ys4[u]);
            float dz = __fsub_rn(cz, zs4[u]);
            float d = __fadd_rn(__fadd_rn(__fmul_rn(dx, dx), __fmul_rn(dy, dy)),
                                __fmul_rn(dz, dz));
            ins4(c0, c1, c2, c3, ((unsigned long long)__float_as_uint(d) << 32) | (p + u));
        }
    }
    int cnt = 4;

    unsigned long long rm0 = 0, rm1 = 0, rm2 = 0, rm3 = 0;
    __shared__ int knn_sh[GRP_K];

    for (int r = 0; r < 16; ++r) {
        // refill any lane whose cache dropped below 2 valid (rare)
        while (true) {
            unsigned long long need = __ballot(cnt < 2);
            if (need == 0ull) break;
            const int wl = __ffsll(need) - 1;
            unsigned long long m0 = __shfl(rm0, wl, 64);
            unsigned long long m1 = __shfl(rm1, wl, 64);
            unsigned long long m2 = __shfl(rm2, wl, 64);
            unsigned long long m3 = __shfl(rm3, wl, 64);
            const int wsel = lane >> 4;
            unsigned long long mw = wsel == 0 ? m0 : (wsel == 1 ? m1 : (wsel == 2 ? m2 : m3));
            // lane covers owner wl's 4 points at j=lane: p = lane*256 + wl*4 + u
            float4 xv = X4[lane * 64 + wl];
            float4 yv = Y4[lane * 64 + wl];
            float4 zv = Z4[lane * 64 + wl];
            float xs4[4] = {xv.x, xv.y, xv.z, xv.w};
            float ys4[4] = {yv.x, yv.y, yv.z, yv.w};
            float zs4[4] = {zv.x, zv.y, zv.z, zv.w};
            unsigned int p = (unsigned int)(lane * 256 + wl * 4);
            unsigned long long s0 = ~0ull, s1 = ~0ull, s2 = ~0ull, s3 = ~0ull;
#pragma unroll
            for (int u = 0; u < 4; ++u) {
                float dx = __fsub_rn(cx, xs4[u]);
                float dy = __fsub_rn(cy, ys4[u]);
                float dz = __fsub_rn(cz, zs4[u]);
                float d = __fadd_rn(__fadd_rn(__fmul_rn(dx, dx), __fmul_rn(dy, dy)),
                                    __fmul_rn(dz, dz));
                unsigned long long v =
                    ((unsigned long long)__float_as_uint(d) << 32) | (p + u);
                if ((mw >> (((lane & 15) << 2) | u)) & 1ull) v = ~0ull;
                ins4(s0, s1, s2, s3, v);
            }
            // butterfly merge of sorted quads -> global top-4 of remaining
#pragma unroll
            for (int m = 1; m < 64; m <<= 1) {
                unsigned long long o0 = __shfl_xor(s0, m, 64);
                unsigned long long o1 = __shfl_xor(s1, m, 64);
                unsigned long long o2 = __shfl_xor(s2, m, 64);
                unsigned long long o3 = __shfl_xor(s3, m, 64);
                ins4(s0, s1, s2, s3, o0);
                ins4(s0, s1, s2, s3, o1);
                ins4(s0, s1, s2, s3, o2);
                ins4(s0, s1, s2, s3, o3);
            }
            if (lane == wl) { c0 = s0; c1 = s1; c2 = s2; c3 = s3; cnt = 4; }
        }

        // exact global top-2 from each lane's best-2 remaining
        unsigned long long r1 = c0, r2 = c1;
#pragma unroll
        for (int m = 1; m < 64; m <<= 1) {
            unsigned long long o1 = __shfl_xor(r1, m, 64);
            unsigned long long o2 = __shfl_xor(r2, m, 64);
            merge2(r1, r2, o1, o2);
        }
        const int q1 = (int)(unsigned int)r1;
        const int q2 = (int)(unsigned int)r2;
        if (lane == 0) { knn_sh[2 * r] = q1; knn_sh[2 * r + 1] = q2; }

        // pops: owner's c0 == extracted key; shift cache, mark removed bit
        const int o1l = (q1 >> 2) & 63;
        if (lane == o1l) {
            const int sl = ((q1 >> 8) << 2) | (q1 & 3);
            unsigned long long bit = 1ull << (sl & 63);
            rm0 |= ((sl >> 6) == 0) ? bit : 0ull;
            rm1 |= ((sl >> 6) == 1) ? bit : 0ull;
            rm2 |= ((sl >> 6) == 2) ? bit : 0ull;
            rm3 |= ((sl >> 6) == 3) ? bit : 0ull;
            c0 = c1; c1 = c2; c2 = c3; c3 = ~0ull; --cnt;
        }
        const int o2l = (q2 >> 2) & 63;
        if (lane == o2l) {
            const int sl = ((q2 >> 8) << 2) | (q2 & 3);
            unsigned long long bit = 1ull << (sl & 63);
            rm0 |= ((sl >> 6) == 0) ? bit : 0ull;
            rm1 |= ((sl >> 6) == 1) ? bit : 0ull;
            rm2 |= ((sl >> 6) == 2) ? bit : 0ull;
            rm3 |= ((sl >> 6) == 3) ? bit : 0ull;
            c0 = c1; c1 = c2; c2 = c3; c3 = ~0ull; --cnt;
        }
    }
    __syncthreads();

    // gather 32 x 6, subtract center from xyz channels
#pragma unroll
    for (int t = 0; t < 3; ++t) {
        int i = lane + 64 * t;
        int k = i / 6, c = i % 6;
        int p = knn_sh[k];
        float val = xb[c * N_PTS + p];
        if (c == 0) val = __fsub_rn(val, cx);
        else if (c == 1) val = __fsub_rn(val, cy);
        else if (c == 2) val = __fsub_rn(val, cz);
        xout[(size_t)bg_out * 192 + i] = val;
    }
}

// ---------------- Phase C: MLP v3 — same M=128 block, 1024 threads (16 waves) ----------------
// v2 used 512 thr + 107.5 KB LDS => 1 block/CU = 2 waves/SIMD: near-zero
// latency hiding for a barrier-heavy MFMA kernel. v3 doubles waves/CU by
// parallelizing the former sequential s-loop M-halves across wave groups:
// wm = w>>3 picks the M-half (rows wm*64..+63), wn = w&7 keeps the old
// N-slice role. Lane-level fragment code, LDS layout, and numerics are
// IDENTICAL to v2 — only the wave->work mapping changed. Per-wave acc state
// halves (acc4 96->48 VGPR) to fit the 128-VGPR cap of 4 waves/SIMD.
__global__ __launch_bounds__(1024) void mlp_mfma_kernel(
    const float* __restrict__ xin,
    const float* __restrict__ w1, const float* __restrict__ b1,
    const float* __restrict__ g1, const float* __restrict__ be1,
    const float* __restrict__ m1, const float* __restrict__ v1,
    const unsigned short* __restrict__ w2t, const float* __restrict__ b2,
    const unsigned short* __restrict__ w3t, const float* __restrict__ b3,
    const float* __restrict__ g2, const float* __restrict__ be2,
    const float* __restrict__ m2, const float* __restrict__ v2,
    const unsigned short* __restrict__ w4t, const float* __restrict__ b4,
    float* __restrict__ out) {
    const int g0 = blockIdx.x * 4;
    const int t = threadIdx.x;
    const int w = t >> 6;        // 0..15
    const int wn = w & 7;        // N-slice (old "w" role)
    const int wm = w >> 3;       // M-half: rows wm*64 .. wm*64+63
    const int lane = t & 63;
    const int lr = lane & 15;
    const int lq = lane >> 4;

    __shared__ __align__(16) unsigned short f2s[128 * 264];
    __shared__ __align__(16) unsigned short ubuf[128 * 136];
    __shared__ __align__(16) unsigned short fgs[4 * 256];
    __shared__ float xs[4 * 192];

    unsigned short* f1s = ubuf;
    unsigned short* f3c = ubuf;

    if (t < 768) xs[t] = xin[(size_t)g0 * 192 + t];
    __syncthreads();

    {
        const int d = t & 127, rq = t >> 7;  // rq in [0,8): 16 rows each
        float wv[6];
#pragma unroll
        for (int c = 0; c < 6; ++c) wv[c] = w1[c * 128 + d];
        const float sc = g1[d] * rsqrtf(v1[d] + EPSF);
        const float sh = be1[d] - m1[d] * sc;
        const float bias = b1[d];

#pragma unroll
        for (int j = 0; j < 16; ++j) {
            const int rl = rq * 16 + j;          // row 0..127
            const int g = rl >> 5, k = rl & 31;
            float acc = bias;
#pragma unroll
            for (int c = 0; c < 6; ++c) acc += xs[g * 192 + k * 6 + c] * wv[c];
            f1s[rl * 136 + d] = f2bf(fmaxf(acc * sc + sh, 0.0f));
        }
        __syncthreads();

        // L2 MFMA: rows wm*64 + mtl*16, cols wn*32 + nti*16
        f32x4 acc[4][2];
#pragma unroll
        for (int nti = 0; nti < 2; ++nti) {
            f32x4 bq = *(const f32x4*)(b2 + wn * 32 + nti * 16 + lq * 4);
#pragma unroll
            for (int mtl = 0; mtl < 4; ++mtl) acc[mtl][nti] = bq;
        }
#pragma unroll
        for (int ks = 0; ks < 4; ++ks) {
            bf16x8 xf[4], wf[2];
#pragma unroll
            for (int mtl = 0; mtl < 4; ++mtl)
                xf[mtl] = *(const bf16x8*)(f1s + (wm * 64 + mtl * 16 + lr) * 136 + ks * 32 + lq * 8);
#pragma unroll
            for (int nti = 0; nti < 2; ++nti)
                wf[nti] = *(const bf16x8*)(w2t + (wn * 32 + nti * 16 + lr) * 128 + ks * 32 + lq * 8);
#pragma unroll
            for (int mtl = 0; mtl < 4; ++mtl)
#pragma unroll
                for (int nti = 0; nti < 2; ++nti)
                    acc[mtl][nti] = __builtin_amdgcn_mfma_f32_16x16x32_bf16(wf[nti], xf[mtl], acc[mtl][nti], 0, 0, 0);
        }
#pragma unroll
        for (int mtl = 0; mtl < 4; ++mtl)
#pragma unroll
            for (int nti = 0; nti < 2; ++nti) {
                bf16x4 p;
#pragma unroll
                for (int r = 0; r < 4; ++r) p[r] = (short)f2bf(acc[mtl][nti][r]);
                *(bf16x4*)(f2s + (size_t)(wm * 64 + mtl * 16 + lr) * 264 + wn * 32 + nti * 16 + lq * 4) = p;
            }
        __syncthreads();
    }

    {
        const int g = t >> 8, n = t & 255;   // 1024 threads: single pass
        float m = -3.9e38f;
#pragma unroll
        for (int k = 0; k < 32; ++k) m = fmaxf(m, bf2f(f2s[(size_t)(g * 32 + k) * 264 + n]));
        fgs[g * 256 + n] = f2bf(m);
    }
    __syncthreads();

    auto ldw3 = [&](int cb_, int ks_) -> bf16x8 {
        return *(const bf16x8*)(w3t + (size_t)(cb_ * 128 + wn * 16 + lr) * 512 + ks_ * 32 + lq * 8);
    };
    auto ldw4 = [&](int cb_, int kl_, int nti_) -> bf16x8 {
        return *(const bf16x8*)(w4t + (size_t)(wn * 48 + nti_ * 16 + lr) * 512 + cb_ * 128 + kl_ * 32 + lq * 8);
    };

    f32x4 acc4[3][4];
#pragma unroll
    for (int nti = 0; nti < 3; ++nti) {
        f32x4 bq = *(const f32x4*)(b4 + wn * 48 + nti * 16 + lq * 4);
#pragma unroll
        for (int ml = 0; ml < 4; ++ml) acc4[nti][ml] = bq;
    }

    for (int cb = 0; cb < 4; ++cb) {
        bf16x8 wp[4];
#pragma unroll
        for (int kp = 0; kp < 4; ++kp) wp[kp] = ldw3(cb, kp);

        // fg-half GEMM (duplicated across wm — 32 MFMA, cheap)
        f32x4 accH = *(const f32x4*)(b3 + cb * 128 + wn * 16 + lq * 4);
#pragma unroll
        for (int ks = 0; ks < 8; ++ks) {
            bf16x8 wf = wp[ks & 3];
            wp[ks & 3] = ldw3(cb, ks + 4);
            bf16x8 xfh = *(const bf16x8*)(fgs + (lr & 3) * 256 + ks * 32 + lq * 8);
            accH = __builtin_amdgcn_mfma_f32_16x16x32_bf16(wf, xfh, accH, 0, 0, 0);
        }
        f32x4 acc3[4];
#pragma unroll
        for (int ml = 0; ml < 4; ++ml) {
            const int gg = (wm * 4 + ml) >> 1;   // global row-tile -> group
#pragma unroll
            for (int r = 0; r < 4; ++r)
                acc3[ml][r] = __shfl(accH[r], (lane & 48) | gg, 64);
        }
#pragma unroll
        for (int ks = 8; ks < 16; ++ks) {
            bf16x8 wf = wp[ks & 3];
            if (ks + 4 < 16) wp[ks & 3] = ldw3(cb, ks + 4);
#pragma unroll
            for (int ml = 0; ml < 4; ++ml) {
                bf16x8 xf = *(const bf16x8*)(f2s + (size_t)(wm * 64 + ml * 16 + lr) * 264 + (ks - 8) * 32 + lq * 8);
                acc3[ml] = __builtin_amdgcn_mfma_f32_16x16x32_bf16(wf, xf, acc3[ml], 0, 0, 0);
            }
        }
        {
            const int nq = cb * 128 + wn * 16 + lq * 4;
            f32x4 g2q = *(const f32x4*)(g2 + nq);
            f32x4 v2q = *(const f32x4*)(v2 + nq);
            f32x4 m2q = *(const f32x4*)(m2 + nq);
            f32x4 beq = *(const f32x4*)(be2 + nq);
            f32x4 sc, sh;
#pragma unroll
            for (int r = 0; r < 4; ++r) {
                sc[r] = g2q[r] * rsqrtf(v2q[r] + EPSF);
                sh[r] = beq[r] - m2q[r] * sc[r];
            }
#pragma unroll
            for (int ml = 0; ml < 4; ++ml) {
                bf16x4 p;
#pragma unroll
                for (int r = 0; r < 4; ++r)
                    p[r] = (short)f2bf(fmaxf(acc3[ml][r] * sc[r] + sh[r], 0.0f));
                *(bf16x4*)(f3c + (size_t)(wm * 64 + ml * 16 + lr) * 136 + wn * 16 + lq * 4) = p;
            }
        }
        bf16x8 w4a[3];
#pragma unroll
        for (int nti = 0; nti < 3; ++nti) w4a[nti] = ldw4(cb, 0, nti);
        __syncthreads();
        for (int kl = 0; kl < 4; ++kl) {
            bf16x8 w4n[3];
            if (kl < 3) {
#pragma unroll
                for (int nti = 0; nti < 3; ++nti) w4n[nti] = ldw4(cb, kl + 1, nti);
            }
            bf16x8 xf8[4];
#pragma unroll
            for (int ml = 0; ml < 4; ++ml)
                xf8[ml] = *(const bf16x8*)(f3c + (size_t)(wm * 64 + ml * 16 + lr) * 136 + kl * 32 + lq * 8);
#pragma unroll
            for (int nti = 0; nti < 3; ++nti)
#pragma unroll
                for (int ml = 0; ml < 4; ++ml)
                    acc4[nti][ml] = __builtin_amdgcn_mfma_f32_16x16x32_bf16(w4a[nti], xf8[ml], acc4[nti][ml], 0, 0, 0);
            if (kl < 3) {
#pragma unroll
                for (int nti = 0; nti < 3; ++nti) w4a[nti] = w4n[nti];
            }
        }
        __syncthreads();
    }

#pragma unroll
    for (int nti = 0; nti < 3; ++nti) {
#pragma unroll
        for (int ggl = 0; ggl < 2; ++ggl) {
            const int gg = wm * 2 + ggl;
            f32x4 vv;
#pragma unroll
            for (int r = 0; r < 4; ++r)
                vv[r] = fmaxf(acc4[nti][2 * ggl][r], acc4[nti][2 * ggl + 1][r]);
#pragma unroll
            for (int mask = 1; mask <= 8; mask <<= 1) {
#pragma unroll
                for (int r = 0; r < 4; ++r)
                    vv[r] = fmaxf(vv[r], __shfl_xor(vv[r], mask, 64));
            }
            if (lr == 0)
                *(f32x4*)(out + (size_t)(g0 + gg) * 384 + wn * 48 + nti * 16 + lq * 4) = vv;
        }
    }
}

extern "C" void kernel_launch(void* const* d_in, const int* in_sizes, int n_in,
                              void* d_out, int out_size, void* d_ws, size_t ws_size,
                              hipStream_t stream) {
    const float* pcd = (const float*)d_in[0];
    const float* w1 = (const float*)d_in[2];
    const float* b1 = (const float*)d_in[3];
    const float* g1 = (const float*)d_in[4];
    const float* be1 = (const float*)d_in[5];
    const float* m1 = (const float*)d_in[6];
    const float* v1 = (const float*)d_in[7];
    const float* w2 = (const float*)d_in[8];
    const float* b2 = (const float*)d_in[9];
    const float* w3 = (const float*)d_in[10];
    const float* b3 = (const float*)d_in[11];
    const float* g2 = (const float*)d_in[12];
    const float* be2 = (const float*)d_in[13];
    const float* m2 = (const float*)d_in[14];
    const float* v2 = (const float*)d_in[15];
    const float* w4 = (const float*)d_in[16];
    const float* b4 = (const float*)d_in[17];
    float* out = (float*)d_out;

    char* ws = (char*)d_ws;
    int* cidx = (int*)ws;                                   // 8192 B
    float* xg = (float*)(ws + 8192);                        // 1,572,864 B
    unsigned short* w2t = (unsigned short*)(ws + 1581056);  // 65,536 B
    unsigned short* w3t = (unsigned short*)(ws + 1646592);  // 524,288 B
    unsigned short* w4t = (unsigned short*)(ws + 2170880);  // 393,216 B

    fps_prep_kernel<<<152, 1024, 0, stream>>>(pcd, cidx, w2, w3, w4, w2t, w3t, w4t);
    knn_kernel<<<2048, 64, 0, stream>>>(pcd, cidx, xg);
    mlp_mfma_kernel<<<512, 1024, 0, stream>>>(xg, w1, b1, g1, be1, m1, v1,
                                              w2t, b2, w3t, b3, g2, be2, m2, v2,
                                              w4t, b4, out);
}

// Round 5
// 407.905 us; speedup vs baseline: 1.0116x; 1.0116x over previous
//
#include <hip/hip_runtime.h>
#include <hip/hip_bf16.h>
#include <math.h>

#define N_PTS 16384
#define NUM_G 64
#define GRP_K 32
#define EPSF 1e-5f

typedef short bf16x8 __attribute__((ext_vector_type(8)));
typedef short bf16x4 __attribute__((ext_vector_type(4)));
typedef float f32x4 __attribute__((ext_vector_type(4)));
typedef unsigned short u16x8 __attribute__((ext_vector_type(8)));

__device__ __forceinline__ unsigned short f2bf(float x) {
    unsigned int u = __builtin_bit_cast(unsigned int, x);
    u = (u + 0x7FFFu + ((u >> 16) & 1u)) >> 16;
    return (unsigned short)u;
}
__device__ __forceinline__ float bf2f(unsigned short h) {
    unsigned int u = ((unsigned int)h) << 16;
    return __builtin_bit_cast(float, u);
}

// ---------------- Fused Phase A: FPS v5 (frozen — structural floor ~126us) + weight prep ----------------
__global__ __launch_bounds__(1024)
__attribute__((amdgpu_waves_per_eu(4, 4)))
void fps_prep_kernel(const float* __restrict__ pcd, int* __restrict__ cidx,
                     const float* __restrict__ w2, const float* __restrict__ w3,
                     const float* __restrict__ w4,
                     unsigned short* __restrict__ w2t,
                     unsigned short* __restrict__ w3t,
                     unsigned short* __restrict__ w4t) {
    __shared__ unsigned long long wk[2][16];
    __shared__ int clds[NUM_G];
    __shared__ unsigned short tl[64][72];

    const int tid = threadIdx.x;

    if (blockIdx.x >= 32) {
        if (tid < 256) {
            const int tile = blockIdx.x - 32;
            const float* src;
            unsigned short* dst;
            int K, N, kt, nt;
            if (tile < 8) {
                src = w2; dst = w2t; K = 128; N = 256;
                kt = tile >> 2; nt = tile & 3;
            } else if (tile < 72) {
                int t2 = tile - 8;
                src = w3; dst = w3t; K = 512; N = 512;
                kt = t2 >> 3; nt = t2 & 7;
            } else {
                int t2 = tile - 72;
                src = w4; dst = w4t; K = 512; N = 384;
                kt = t2 / 6; nt = t2 % 6;
            }
            const int k0 = kt * 64, n0 = nt * 64;
            const int c = tid & 63, r0 = tid >> 6;
#pragma unroll
            for (int i = 0; i < 16; ++i) {
                int r = 4 * i + r0;
                tl[r][c] = f2bf(src[(size_t)(k0 + r) * N + n0 + c]);
            }
            __syncthreads();
            const int n = tid >> 2;
            const int kc = (tid & 3) * 16;
            u16x8 v0, v1;
#pragma unroll
            for (int j = 0; j < 8; ++j) {
                v0[j] = tl[kc + j][n];
                v1[j] = tl[kc + 8 + j][n];
            }
            *(u16x8*)(dst + (size_t)(n0 + n) * K + k0 + kc) = v0;
            *(u16x8*)(dst + (size_t)(n0 + n) * K + k0 + kc + 8) = v1;
        } else {
            __syncthreads();
        }
        return;
    }

    const int b = blockIdx.x;
    const int lane = tid & 63, w = tid >> 6;
    const float* xb = pcd + (size_t)b * 6 * N_PTS;
    const float4* Xc = (const float4*)xb;
    const float4* Yc = (const float4*)(xb + N_PTS);
    const float4* Zc = (const float4*)(xb + 2 * N_PTS);

    float dist[16];
#pragma unroll
    for (int j = 0; j < 16; ++j) dist[j] = 1e10f;

    int far = 0;
    for (int it = 0; it < NUM_G; ++it) {
        int fu = __builtin_amdgcn_readfirstlane(far);
        float cx = xb[fu], cy = xb[N_PTS + fu], cz = xb[2 * N_PTS + fu];
        if (tid == 0) clds[it] = fu;

        float bv = -1.0f;
        int bj = 0;
#pragma unroll
        for (int jp = 0; jp < 4; ++jp) {
            float4 xq = Xc[tid * 4 + jp];
            float4 yq = Yc[tid * 4 + jp];
            float4 zq = Zc[tid * 4 + jp];
            float xa[4] = {xq.x, xq.y, xq.z, xq.w};
            float ya[4] = {yq.x, yq.y, yq.z, yq.w};
            float za[4] = {zq.x, zq.y, zq.z, zq.w};
#pragma unroll
            for (int u = 0; u < 4; ++u) {
                const int j = jp * 4 + u;
                float dx = __fsub_rn(xa[u], cx);
                float dy = __fsub_rn(ya[u], cy);
                float dz = __fsub_rn(za[u], cz);
                float d = __fadd_rn(__fadd_rn(__fmul_rn(dx, dx), __fmul_rn(dy, dy)),
                                    __fmul_rn(dz, dz));
                dist[j] = fminf(dist[j], d);
                if (dist[j] > bv) { bv = dist[j]; bj = j; }
            }
        }
        float vmax = bv;
#pragma unroll
        for (int m = 1; m < 64; m <<= 1) {
            float o = __shfl_xor(vmax, m, 64);
            vmax = o > vmax ? o : vmax;
        }
        unsigned long long mk = __ballot(bv == vmax);
        int fl = __ffsll((unsigned long long)mk) - 1;
        int bjw = __shfl(bj, fl, 64);
        int idx = (((w << 6) | fl) << 4) + bjw;
        unsigned long long key =
            ((unsigned long long)__float_as_uint(vmax) << 32) | (unsigned int)~idx;
        if (lane == 0) wk[it & 1][w] = key;
        __syncthreads();
        unsigned long long k2 = (lane < 16) ? wk[it & 1][lane] : 0ull;
#pragma unroll
        for (int m = 1; m < 16; m <<= 1) {
            unsigned long long o = __shfl_xor(k2, m, 64);
            k2 = o > k2 ? o : k2;
        }
        k2 = __shfl(k2, 0, 64);
        far = (int)(~(unsigned int)k2);
    }
    __syncthreads();
    if (tid < NUM_G) cidx[b * NUM_G + tid] = clds[tid];
}

// ---------------- Phase B: KNN v3 — lazy top-4 cache, one wave per group (unchanged) ----------------
__device__ __forceinline__ void merge2(unsigned long long& a1, unsigned long long& a2,
                                       unsigned long long o1, unsigned long long o2) {
    unsigned long long hi = a1 > o1 ? a1 : o1;
    a1 = a1 < o1 ? a1 : o1;
    unsigned long long lo2 = a2 < o2 ? a2 : o2;
    a2 = hi < lo2 ? hi : lo2;
}
// sorted ascending insert of v into (c0<=c1<=c2<=c3), keeping 4 smallest
__device__ __forceinline__ void ins4(unsigned long long& c0, unsigned long long& c1,
                                     unsigned long long& c2, unsigned long long& c3,
                                     unsigned long long v) {
    if (v < c3) {
        unsigned long long t3 = c2 > v ? c2 : v;
        unsigned long long t2 = c2 > v ? v : c2;
        unsigned long long u2 = c1 > t2 ? c1 : t2;
        unsigned long long u1 = c1 > t2 ? t2 : c1;
        unsigned long long s1 = c0 > u1 ? c0 : u1;
        unsigned long long s0 = c0 > u1 ? u1 : c0;
        c0 = s0; c1 = s1; c2 = u2; c3 = t3;
    }
}

__global__ __launch_bounds__(64)
__attribute__((amdgpu_waves_per_eu(4, 4)))
void knn_kernel(const float* __restrict__ pcd,
                const int* __restrict__ cidx,
                float* __restrict__ xout) {
    const int b = blockIdx.x & 31;       // XCD-locality swizzle
    const int g = blockIdx.x >> 5;
    const int bg_out = b * NUM_G + g;
    const int lane = threadIdx.x;
    const float* xb = pcd + (size_t)b * 6 * N_PTS;

    const int ci = cidx[bg_out];
    const float cx = xb[ci], cy = xb[N_PTS + ci], cz = xb[2 * N_PTS + ci];

    const float4* X4 = (const float4*)xb;
    const float4* Y4 = (const float4*)(xb + N_PTS);
    const float4* Z4 = (const float4*)(xb + 2 * N_PTS);

    // per-lane sorted top-4 cache of its 256 points p = j*256 + lane*4 + u
    unsigned long long c0 = ~0ull, c1 = ~0ull, c2 = ~0ull, c3 = ~0ull;
#pragma unroll 8
    for (int j = 0; j < 64; ++j) {
        float4 xv = X4[j * 64 + lane];
        float4 yv = Y4[j * 64 + lane];
        float4 zv = Z4[j * 64 + lane];
        float xs4[4] = {xv.x, xv.y, xv.z, xv.w};
        float ys4[4] = {yv.x, yv.y, yv.z, yv.w};
        float zs4[4] = {zv.x, zv.y, zv.z, zv.w};
        unsigned int p = (unsigned int)(j * 256 + lane * 4);
#pragma unroll
        for (int u = 0; u < 4; ++u) {
            float dx = __fsub_rn(cx, xs4[u]);
            float dy = __fsub_rn(cy, ys4[u]);
            float dz = __fsub_rn(cz, zs4[u]);
            float d = __fadd_rn(__fadd_rn(__fmul_rn(dx, dx), __fmul_rn(dy, dy)),
                                __fmul_rn(dz, dz));
            ins4(c0, c1, c2, c3, ((unsigned long long)__float_as_uint(d) << 32) | (p + u));
        }
    }
    int cnt = 4;

    unsigned long long rm0 = 0, rm1 = 0, rm2 = 0, rm3 = 0;
    __shared__ int knn_sh[GRP_K];

    for (int r = 0; r < 16; ++r) {
        // refill any lane whose cache dropped below 2 valid (rare)
        while (true) {
            unsigned long long need = __ballot(cnt < 2);
            if (need == 0ull) break;
            const int wl = __ffsll(need) - 1;
            unsigned long long m0 = __shfl(rm0, wl, 64);
            unsigned long long m1 = __shfl(rm1, wl, 64);
            unsigned long long m2 = __shfl(rm2, wl, 64);
            unsigned long long m3 = __shfl(rm3, wl, 64);
            const int wsel = lane >> 4;
            unsigned long long mw = wsel == 0 ? m0 : (wsel == 1 ? m1 : (wsel == 2 ? m2 : m3));
            // lane covers owner wl's 4 points at j=lane: p = lane*256 + wl*4 + u
            float4 xv = X4[lane * 64 + wl];
            float4 yv = Y4[lane * 64 + wl];
            float4 zv = Z4[lane * 64 + wl];
            float xs4[4] = {xv.x, xv.y, xv.z, xv.w};
            float ys4[4] = {yv.x, yv.y, yv.z, yv.w};
            float zs4[4] = {zv.x, zv.y, zv.z, zv.w};
            unsigned int p = (unsigned int)(lane * 256 + wl * 4);
            unsigned long long s0 = ~0ull, s1 = ~0ull, s2 = ~0ull, s3 = ~0ull;
#pragma unroll
            for (int u = 0; u < 4; ++u) {
                float dx = __fsub_rn(cx, xs4[u]);
                float dy = __fsub_rn(cy, ys4[u]);
                float dz = __fsub_rn(cz, zs4[u]);
                float d = __fadd_rn(__fadd_rn(__fmul_rn(dx, dx), __fmul_rn(dy, dy)),
                                    __fmul_rn(dz, dz));
                unsigned long long v =
                    ((unsigned long long)__float_as_uint(d) << 32) | (p + u);
                if ((mw >> (((lane & 15) << 2) | u)) & 1ull) v = ~0ull;
                ins4(s0, s1, s2, s3, v);
            }
            // butterfly merge of sorted quads -> global top-4 of remaining
#pragma unroll
            for (int m = 1; m < 64; m <<= 1) {
                unsigned long long o0 = __shfl_xor(s0, m, 64);
                unsigned long long o1 = __shfl_xor(s1, m, 64);
                unsigned long long o2 = __shfl_xor(s2, m, 64);
                unsigned long long o3 = __shfl_xor(s3, m, 64);
                ins4(s0, s1, s2, s3, o0);
                ins4(s0, s1, s2, s3, o1);
                ins4(s0, s1, s2, s3, o2);
                ins4(s0, s1, s2, s3, o3);
            }
            if (lane == wl) { c0 = s0; c1 = s1; c2 = s2; c3 = s3; cnt = 4; }
        }

        // exact global top-2 from each lane's best-2 remaining
        unsigned long long r1 = c0, r2 = c1;
#pragma unroll
        for (int m = 1; m < 64; m <<= 1) {
            unsigned long long o1 = __shfl_xor(r1, m, 64);
            unsigned long long o2 = __shfl_xor(r2, m, 64);
            merge2(r1, r2, o1, o2);
        }
        const int q1 = (int)(unsigned int)r1;
        const int q2 = (int)(unsigned int)r2;
        if (lane == 0) { knn_sh[2 * r] = q1; knn_sh[2 * r + 1] = q2; }

        // pops: owner's c0 == extracted key; shift cache, mark removed bit
        const int o1l = (q1 >> 2) & 63;
        if (lane == o1l) {
            const int sl = ((q1 >> 8) << 2) | (q1 & 3);
            unsigned long long bit = 1ull << (sl & 63);
            rm0 |= ((sl >> 6) == 0) ? bit : 0ull;
            rm1 |= ((sl >> 6) == 1) ? bit : 0ull;
            rm2 |= ((sl >> 6) == 2) ? bit : 0ull;
            rm3 |= ((sl >> 6) == 3) ? bit : 0ull;
            c0 = c1; c1 = c2; c2 = c3; c3 = ~0ull; --cnt;
        }
        const int o2l = (q2 >> 2) & 63;
        if (lane == o2l) {
            const int sl = ((q2 >> 8) << 2) | (q2 & 3);
            unsigned long long bit = 1ull << (sl & 63);
            rm0 |= ((sl >> 6) == 0) ? bit : 0ull;
            rm1 |= ((sl >> 6) == 1) ? bit : 0ull;
            rm2 |= ((sl >> 6) == 2) ? bit : 0ull;
            rm3 |= ((sl >> 6) == 3) ? bit : 0ull;
            c0 = c1; c1 = c2; c2 = c3; c3 = ~0ull; --cnt;
        }
    }
    __syncthreads();

    // gather 32 x 6, subtract center from xyz channels
#pragma unroll
    for (int t = 0; t < 3; ++t) {
        int i = lane + 64 * t;
        int k = i / 6, c = i % 6;
        int p = knn_sh[k];
        float val = xb[c * N_PTS + p];
        if (c == 0) val = __fsub_rn(val, cx);
        else if (c == 1) val = __fsub_rn(val, cy);
        else if (c == 2) val = __fsub_rn(val, cz);
        xout[(size_t)bg_out * 192 + i] = val;
    }
}

// ---------------- Phase C: MLP v4 — M=64 half-block, 512 thr, 2 independent blocks/CU ----------------
// v2 (M=128, 107.5KB LDS, 1 block/CU): MFMA-busy only ~5us/CU vs ~120us runtime
// => 95% stall on the serialized stage chain; every barrier syncs the whole CU.
// v3 showed more waves in ONE barrier domain makes it worse. v4 keeps v2's
// lane-level code verbatim but halves the block to 2 groups (M=64): LDS
// ~53.5KB => 2 INDEPENDENT blocks resident per CU whose stalls overlap.
// fgs keeps 4 group-rows (2 real + 2 zeroed) so the verified accH/shfl
// group-broadcast path is byte-identical to v2.
__global__ __launch_bounds__(512, 4) void mlp_mfma_kernel(
    const float* __restrict__ xin,
    const float* __restrict__ w1, const float* __restrict__ b1,
    const float* __restrict__ g1, const float* __restrict__ be1,
    const float* __restrict__ m1, const float* __restrict__ v1,
    const unsigned short* __restrict__ w2t, const float* __restrict__ b2,
    const unsigned short* __restrict__ w3t, const float* __restrict__ b3,
    const float* __restrict__ g2, const float* __restrict__ be2,
    const float* __restrict__ m2, const float* __restrict__ v2,
    const unsigned short* __restrict__ w4t, const float* __restrict__ b4,
    float* __restrict__ out) {
    const int g0 = blockIdx.x * 2;
    const int t = threadIdx.x;
    const int w = t >> 6;
    const int lane = t & 63;
    const int lr = lane & 15;
    const int lq = lane >> 4;

    __shared__ __align__(16) unsigned short f2s[64 * 264];
    __shared__ __align__(16) unsigned short ubuf[64 * 136];
    __shared__ __align__(16) unsigned short fgs[4 * 256];
    __shared__ float xs[2 * 192];

    unsigned short* f1s = ubuf;
    unsigned short* f3c = ubuf;

    if (t < 384) xs[t] = xin[(size_t)g0 * 192 + t];
    __syncthreads();

    {
        const int d = t & 127, rq = t >> 7;  // rq in [0,4): 16 rows each
        float wv[6];
#pragma unroll
        for (int c = 0; c < 6; ++c) wv[c] = w1[c * 128 + d];
        const float sc = g1[d] * rsqrtf(v1[d] + EPSF);
        const float sh = be1[d] - m1[d] * sc;
        const float bias = b1[d];

#pragma unroll
        for (int j = 0; j < 16; ++j) {
            const int rl = rq * 16 + j;          // row 0..63
            const int g = rl >> 5, k = rl & 31;
            float acc = bias;
#pragma unroll
            for (int c = 0; c < 6; ++c) acc += xs[g * 192 + k * 6 + c] * wv[c];
            f1s[rl * 136 + d] = f2bf(fmaxf(acc * sc + sh, 0.0f));
        }
        __syncthreads();

        // L2 MFMA (exactly v2's single s-half): rows mtl*16, cols w*32 + nti*16
        f32x4 acc[4][2];
#pragma unroll
        for (int nti = 0; nti < 2; ++nti) {
            f32x4 bq = *(const f32x4*)(b2 + w * 32 + nti * 16 + lq * 4);
#pragma unroll
            for (int mtl = 0; mtl < 4; ++mtl) acc[mtl][nti] = bq;
        }
#pragma unroll
        for (int ks = 0; ks < 4; ++ks) {
            bf16x8 xf[4], wf[2];
#pragma unroll
            for (int mtl = 0; mtl < 4; ++mtl)
                xf[mtl] = *(const bf16x8*)(f1s + (mtl * 16 + lr) * 136 + ks * 32 + lq * 8);
#pragma unroll
            for (int nti = 0; nti < 2; ++nti)
                wf[nti] = *(const bf16x8*)(w2t + (w * 32 + nti * 16 + lr) * 128 + ks * 32 + lq * 8);
#pragma unroll
            for (int mtl = 0; mtl < 4; ++mtl)
#pragma unroll
                for (int nti = 0; nti < 2; ++nti)
                    acc[mtl][nti] = __builtin_amdgcn_mfma_f32_16x16x32_bf16(wf[nti], xf[mtl], acc[mtl][nti], 0, 0, 0);
        }
#pragma unroll
        for (int mtl = 0; mtl < 4; ++mtl)
#pragma unroll
            for (int nti = 0; nti < 2; ++nti) {
                bf16x4 p;
#pragma unroll
                for (int r = 0; r < 4; ++r) p[r] = (short)f2bf(acc[mtl][nti][r]);
                *(bf16x4*)(f2s + (size_t)(mtl * 16 + lr) * 264 + w * 32 + nti * 16 + lq * 4) = p;
            }
        __syncthreads();
    }

    {
        // group-max into fgs rows 0..1; zero rows 2..3 (accH safety, see header)
        const int g = t >> 8, n = t & 255;   // 512 threads cover 2x256
        float m = -3.9e38f;
#pragma unroll
        for (int k = 0; k < 32; ++k) m = fmaxf(m, bf2f(f2s[(size_t)(g * 32 + k) * 264 + n]));
        fgs[g * 256 + n] = f2bf(m);
        fgs[512 + t] = 0;
    }
    __syncthreads();

    auto ldw3 = [&](int cb_, int ks_) -> bf16x8 {
        return *(const bf16x8*)(w3t + (size_t)(cb_ * 128 + w * 16 + lr) * 512 + ks_ * 32 + lq * 8);
    };
    auto ldw4 = [&](int cb_, int kl_, int nti_) -> bf16x8 {
        return *(const bf16x8*)(w4t + (size_t)(w * 48 + nti_ * 16 + lr) * 512 + cb_ * 128 + kl_ * 32 + lq * 8);
    };

    f32x4 acc4[3][4];
#pragma unroll
    for (int nti = 0; nti < 3; ++nti) {
        f32x4 bq = *(const f32x4*)(b4 + w * 48 + nti * 16 + lq * 4);
#pragma unroll
        for (int ml = 0; ml < 4; ++ml) acc4[nti][ml] = bq;
    }

    for (int cb = 0; cb < 4; ++cb) {
        bf16x8 wp[4];
#pragma unroll
        for (int kp = 0; kp < 4; ++kp) wp[kp] = ldw3(cb, kp);

        // fg-half GEMM
        f32x4 accH = *(const f32x4*)(b3 + cb * 128 + w * 16 + lq * 4);
#pragma unroll
        for (int ks = 0; ks < 8; ++ks) {
            bf16x8 wf = wp[ks & 3];
            wp[ks & 3] = ldw3(cb, ks + 4);
            bf16x8 xfh = *(const bf16x8*)(fgs + (lr & 3) * 256 + ks * 32 + lq * 8);
            accH = __builtin_amdgcn_mfma_f32_16x16x32_bf16(wf, xfh, accH, 0, 0, 0);
        }
        f32x4 acc3[4];
#pragma unroll
        for (int ml = 0; ml < 4; ++ml) {
            const int gg = ml >> 1;              // group of row-tile ml
#pragma unroll
            for (int r = 0; r < 4; ++r)
                acc3[ml][r] = __shfl(accH[r], (lane & 48) | gg, 64);
        }
#pragma unroll
        for (int ks = 8; ks < 16; ++ks) {
            bf16x8 wf = wp[ks & 3];
            if (ks + 4 < 16) wp[ks & 3] = ldw3(cb, ks + 4);
#pragma unroll
            for (int ml = 0; ml < 4; ++ml) {
                bf16x8 xf = *(const bf16x8*)(f2s + (size_t)(ml * 16 + lr) * 264 + (ks - 8) * 32 + lq * 8);
                acc3[ml] = __builtin_amdgcn_mfma_f32_16x16x32_bf16(wf, xf, acc3[ml], 0, 0, 0);
            }
        }
        {
            const int nq = cb * 128 + w * 16 + lq * 4;
            f32x4 g2q = *(const f32x4*)(g2 + nq);
            f32x4 v2q = *(const f32x4*)(v2 + nq);
            f32x4 m2q = *(const f32x4*)(m2 + nq);
            f32x4 beq = *(const f32x4*)(be2 + nq);
            f32x4 sc, sh;
#pragma unroll
            for (int r = 0; r < 4; ++r) {
                sc[r] = g2q[r] * rsqrtf(v2q[r] + EPSF);
                sh[r] = beq[r] - m2q[r] * sc[r];
            }
#pragma unroll
            for (int ml = 0; ml < 4; ++ml) {
                bf16x4 p;
#pragma unroll
                for (int r = 0; r < 4; ++r)
                    p[r] = (short)f2bf(fmaxf(acc3[ml][r] * sc[r] + sh[r], 0.0f));
                *(bf16x4*)(f3c + (size_t)(ml * 16 + lr) * 136 + w * 16 + lq * 4) = p;
            }
        }
        bf16x8 w4a[3];
#pragma unroll
        for (int nti = 0; nti < 3; ++nti) w4a[nti] = ldw4(cb, 0, nti);
        __syncthreads();
        for (int kl = 0; kl < 4; ++kl) {
            bf16x8 w4n[3];
            if (kl < 3) {
#pragma unroll
                for (int nti = 0; nti < 3; ++nti) w4n[nti] = ldw4(cb, kl + 1, nti);
            }
            bf16x8 xf8[4];
#pragma unroll
            for (int ml = 0; ml < 4; ++ml)
                xf8[ml] = *(const bf16x8*)(f3c + (size_t)(ml * 16 + lr) * 136 + kl * 32 + lq * 8);
#pragma unroll
            for (int nti = 0; nti < 3; ++nti)
#pragma unroll
                for (int ml = 0; ml < 4; ++ml)
                    acc4[nti][ml] = __builtin_amdgcn_mfma_f32_16x16x32_bf16(w4a[nti], xf8[ml], acc4[nti][ml], 0, 0, 0);
            if (kl < 3) {
#pragma unroll
                for (int nti = 0; nti < 3; ++nti) w4a[nti] = w4n[nti];
            }
        }
        __syncthreads();
    }

#pragma unroll
    for (int nti = 0; nti < 3; ++nti) {
#pragma unroll
        for (int gg = 0; gg < 2; ++gg) {
            f32x4 vv;
#pragma unroll
            for (int r = 0; r < 4; ++r)
                vv[r] = fmaxf(acc4[nti][2 * gg][r], acc4[nti][2 * gg + 1][r]);
#pragma unroll
            for (int mask = 1; mask <= 8; mask <<= 1) {
#pragma unroll
                for (int r = 0; r < 4; ++r)
                    vv[r] = fmaxf(vv[r], __shfl_xor(vv[r], mask, 64));
            }
            if (lr == 0)
                *(f32x4*)(out + (size_t)(g0 + gg) * 384 + w * 48 + nti * 16 + lq * 4) = vv;
        }
    }
}

extern "C" void kernel_launch(void* const* d_in, const int* in_sizes, int n_in,
                              void* d_out, int out_size, void* d_ws, size_t ws_size,
                              hipStream_t stream) {
    const float* pcd = (const float*)d_in[0];
    const float* w1 = (const float*)d_in[2];
    const float* b1 = (const float*)d_in[3];
    const float* g1 = (const float*)d_in[4];
    const float* be1 = (const float*)d_in[5];
    const float* m1 = (const float*)d_in[6];
    const float* v1 = (const float*)d_in[7];
    const float* w2 = (const float*)d_in[8];
    const float* b2 = (const float*)d_in[9];
    const float* w3 = (const float*)d_in[10];
    const float* b3 = (const float*)d_in[11];
    const float* g2 = (const float*)d_in[12];
    const float* be2 = (const float*)d_in[13];
    const float* m2 = (const float*)d_in[14];
    const float* v2 = (const float*)d_in[15];
    const float* w4 = (const float*)d_in[16];
    const float* b4 = (const float*)d_in[17];
    float* out = (float*)d_out;

    char* ws = (char*)d_ws;
    int* cidx = (int*)ws;                                   // 8192 B
    float* xg = (float*)(ws + 8192);                        // 1,572,864 B
    unsigned short* w2t = (unsigned short*)(ws + 1581056);  // 65,536 B
    unsigned short* w3t = (unsigned short*)(ws + 1646592);  // 524,288 B
    unsigned short* w4t = (unsigned short*)(ws + 2170880);  // 393,216 B

    fps_prep_kernel<<<152, 1024, 0, stream>>>(pcd, cidx, w2, w3, w4, w2t, w3t, w4t);
    knn_kernel<<<2048, 64, 0, stream>>>(pcd, cidx, xg);
    mlp_mfma_kernel<<<1024, 512, 0, stream>>>(xg, w1, b1, g1, be1, m1, v1,
                                              w2t, b2, w3t, b3, g2, be2, m2, v2,
                                              w4t, b4, out);
}

// Round 6
// 394.711 us; speedup vs baseline: 1.0454x; 1.0334x over previous
//
#include <hip/hip_runtime.h>
#include <hip/hip_bf16.h>
#include <math.h>

#define N_PTS 16384
#define NUM_G 64
#define GRP_K 32
#define EPSF 1e-5f

typedef short bf16x8 __attribute__((ext_vector_type(8)));
typedef short bf16x4 __attribute__((ext_vector_type(4)));
typedef float f32x4 __attribute__((ext_vector_type(4)));
typedef unsigned short u16x8 __attribute__((ext_vector_type(8)));

__device__ __forceinline__ unsigned short f2bf(float x) {
    unsigned int u = __builtin_bit_cast(unsigned int, x);
    u = (u + 0x7FFFu + ((u >> 16) & 1u)) >> 16;
    return (unsigned short)u;
}
__device__ __forceinline__ float bf2f(unsigned short h) {
    unsigned int u = ((unsigned int)h) << 16;
    return __builtin_bit_cast(float, u);
}

// ---------------- Fused Phase A: FPS v5 (frozen — structural floor ~126us) + weight prep ----------------
__global__ __launch_bounds__(1024)
__attribute__((amdgpu_waves_per_eu(4, 4)))
void fps_prep_kernel(const float* __restrict__ pcd, int* __restrict__ cidx,
                     const float* __restrict__ w2, const float* __restrict__ w3,
                     const float* __restrict__ w4,
                     unsigned short* __restrict__ w2t,
                     unsigned short* __restrict__ w3t,
                     unsigned short* __restrict__ w4t) {
    __shared__ unsigned long long wk[2][16];
    __shared__ int clds[NUM_G];
    __shared__ unsigned short tl[64][72];

    const int tid = threadIdx.x;

    if (blockIdx.x >= 32) {
        if (tid < 256) {
            const int tile = blockIdx.x - 32;
            const float* src;
            unsigned short* dst;
            int K, N, kt, nt;
            if (tile < 8) {
                src = w2; dst = w2t; K = 128; N = 256;
                kt = tile >> 2; nt = tile & 3;
            } else if (tile < 72) {
                int t2 = tile - 8;
                src = w3; dst = w3t; K = 512; N = 512;
                kt = t2 >> 3; nt = t2 & 7;
            } else {
                int t2 = tile - 72;
                src = w4; dst = w4t; K = 512; N = 384;
                kt = t2 / 6; nt = t2 % 6;
            }
            const int k0 = kt * 64, n0 = nt * 64;
            const int c = tid & 63, r0 = tid >> 6;
#pragma unroll
            for (int i = 0; i < 16; ++i) {
                int r = 4 * i + r0;
                tl[r][c] = f2bf(src[(size_t)(k0 + r) * N + n0 + c]);
            }
            __syncthreads();
            const int n = tid >> 2;
            const int kc = (tid & 3) * 16;
            u16x8 v0, v1;
#pragma unroll
            for (int j = 0; j < 8; ++j) {
                v0[j] = tl[kc + j][n];
                v1[j] = tl[kc + 8 + j][n];
            }
            *(u16x8*)(dst + (size_t)(n0 + n) * K + k0 + kc) = v0;
            *(u16x8*)(dst + (size_t)(n0 + n) * K + k0 + kc + 8) = v1;
        } else {
            __syncthreads();
        }
        return;
    }

    const int b = blockIdx.x;
    const int lane = tid & 63, w = tid >> 6;
    const float* xb = pcd + (size_t)b * 6 * N_PTS;
    const float4* Xc = (const float4*)xb;
    const float4* Yc = (const float4*)(xb + N_PTS);
    const float4* Zc = (const float4*)(xb + 2 * N_PTS);

    float dist[16];
#pragma unroll
    for (int j = 0; j < 16; ++j) dist[j] = 1e10f;

    int far = 0;
    for (int it = 0; it < NUM_G; ++it) {
        int fu = __builtin_amdgcn_readfirstlane(far);
        float cx = xb[fu], cy = xb[N_PTS + fu], cz = xb[2 * N_PTS + fu];
        if (tid == 0) clds[it] = fu;

        float bv = -1.0f;
        int bj = 0;
#pragma unroll
        for (int jp = 0; jp < 4; ++jp) {
            float4 xq = Xc[tid * 4 + jp];
            float4 yq = Yc[tid * 4 + jp];
            float4 zq = Zc[tid * 4 + jp];
            float xa[4] = {xq.x, xq.y, xq.z, xq.w};
            float ya[4] = {yq.x, yq.y, yq.z, yq.w};
            float za[4] = {zq.x, zq.y, zq.z, zq.w};
#pragma unroll
            for (int u = 0; u < 4; ++u) {
                const int j = jp * 4 + u;
                float dx = __fsub_rn(xa[u], cx);
                float dy = __fsub_rn(ya[u], cy);
                float dz = __fsub_rn(za[u], cz);
                float d = __fadd_rn(__fadd_rn(__fmul_rn(dx, dx), __fmul_rn(dy, dy)),
                                    __fmul_rn(dz, dz));
                dist[j] = fminf(dist[j], d);
                if (dist[j] > bv) { bv = dist[j]; bj = j; }
            }
        }
        float vmax = bv;
#pragma unroll
        for (int m = 1; m < 64; m <<= 1) {
            float o = __shfl_xor(vmax, m, 64);
            vmax = o > vmax ? o : vmax;
        }
        unsigned long long mk = __ballot(bv == vmax);
        int fl = __ffsll((unsigned long long)mk) - 1;
        int bjw = __shfl(bj, fl, 64);
        int idx = (((w << 6) | fl) << 4) + bjw;
        unsigned long long key =
            ((unsigned long long)__float_as_uint(vmax) << 32) | (unsigned int)~idx;
        if (lane == 0) wk[it & 1][w] = key;
        __syncthreads();
        unsigned long long k2 = (lane < 16) ? wk[it & 1][lane] : 0ull;
#pragma unroll
        for (int m = 1; m < 16; m <<= 1) {
            unsigned long long o = __shfl_xor(k2, m, 64);
            k2 = o > k2 ? o : k2;
        }
        k2 = __shfl(k2, 0, 64);
        far = (int)(~(unsigned int)k2);
    }
    __syncthreads();
    if (tid < NUM_G) cidx[b * NUM_G + tid] = clds[tid];
}

// ---------------- Phase B: KNN v4 — 4 groups per 256-thr workgroup ----------------
// Totals arithmetic (R4/R5) puts knn at ~135us vs ~11us of serial per-wave
// work: consistent with ~1 resident wave/CU under 64-thr workgroups +
// waves_per_eu(4,4) (R1 counter row showed Occupancy 3.2%). v4 packs 4
// groups (one per wave) into a 256-thr workgroup and drops the waves_per_eu
// cap; the per-wave algorithm is textually identical. Same-batch groups now
// also share L2 reads of the 196KB xyz slab.
__device__ __forceinline__ void merge2(unsigned long long& a1, unsigned long long& a2,
                                       unsigned long long o1, unsigned long long o2) {
    unsigned long long hi = a1 > o1 ? a1 : o1;
    a1 = a1 < o1 ? a1 : o1;
    unsigned long long lo2 = a2 < o2 ? a2 : o2;
    a2 = hi < lo2 ? hi : lo2;
}
// sorted ascending insert of v into (c0<=c1<=c2<=c3), keeping 4 smallest
__device__ __forceinline__ void ins4(unsigned long long& c0, unsigned long long& c1,
                                     unsigned long long& c2, unsigned long long& c3,
                                     unsigned long long v) {
    if (v < c3) {
        unsigned long long t3 = c2 > v ? c2 : v;
        unsigned long long t2 = c2 > v ? v : c2;
        unsigned long long u2 = c1 > t2 ? c1 : t2;
        unsigned long long u1 = c1 > t2 ? t2 : c1;
        unsigned long long s1 = c0 > u1 ? c0 : u1;
        unsigned long long s0 = c0 > u1 ? u1 : c0;
        c0 = s0; c1 = s1; c2 = u2; c3 = t3;
    }
}

__global__ __launch_bounds__(256)
void knn_kernel(const float* __restrict__ pcd,
                const int* __restrict__ cidx,
                float* __restrict__ xout) {
    const int b = blockIdx.x & 31;             // XCD-locality swizzle
    const int wave = threadIdx.x >> 6;
    const int g = (blockIdx.x >> 5) * 4 + wave;
    const int bg_out = b * NUM_G + g;
    const int lane = threadIdx.x & 63;
    const float* xb = pcd + (size_t)b * 6 * N_PTS;

    const int ci = cidx[bg_out];
    const float cx = xb[ci], cy = xb[N_PTS + ci], cz = xb[2 * N_PTS + ci];

    const float4* X4 = (const float4*)xb;
    const float4* Y4 = (const float4*)(xb + N_PTS);
    const float4* Z4 = (const float4*)(xb + 2 * N_PTS);

    // per-lane sorted top-4 cache of its 256 points p = j*256 + lane*4 + u
    unsigned long long c0 = ~0ull, c1 = ~0ull, c2 = ~0ull, c3 = ~0ull;
#pragma unroll 8
    for (int j = 0; j < 64; ++j) {
        float4 xv = X4[j * 64 + lane];
        float4 yv = Y4[j * 64 + lane];
        float4 zv = Z4[j * 64 + lane];
        float xs4[4] = {xv.x, xv.y, xv.z, xv.w};
        float ys4[4] = {yv.x, yv.y, yv.z, yv.w};
        float zs4[4] = {zv.x, zv.y, zv.z, zv.w};
        unsigned int p = (unsigned int)(j * 256 + lane * 4);
#pragma unroll
        for (int u = 0; u < 4; ++u) {
            float dx = __fsub_rn(cx, xs4[u]);
            float dy = __fsub_rn(cy, ys4[u]);
            float dz = __fsub_rn(cz, zs4[u]);
            float d = __fadd_rn(__fadd_rn(__fmul_rn(dx, dx), __fmul_rn(dy, dy)),
                                __fmul_rn(dz, dz));
            ins4(c0, c1, c2, c3, ((unsigned long long)__float_as_uint(d) << 32) | (p + u));
        }
    }
    int cnt = 4;

    unsigned long long rm0 = 0, rm1 = 0, rm2 = 0, rm3 = 0;
    __shared__ int knn_sh[4][GRP_K];

    for (int r = 0; r < 16; ++r) {
        // refill any lane whose cache dropped below 2 valid (rare)
        while (true) {
            unsigned long long need = __ballot(cnt < 2);
            if (need == 0ull) break;
            const int wl = __ffsll(need) - 1;
            unsigned long long m0 = __shfl(rm0, wl, 64);
            unsigned long long m1 = __shfl(rm1, wl, 64);
            unsigned long long m2 = __shfl(rm2, wl, 64);
            unsigned long long m3 = __shfl(rm3, wl, 64);
            const int wsel = lane >> 4;
            unsigned long long mw = wsel == 0 ? m0 : (wsel == 1 ? m1 : (wsel == 2 ? m2 : m3));
            // lane covers owner wl's 4 points at j=lane: p = lane*256 + wl*4 + u
            float4 xv = X4[lane * 64 + wl];
            float4 yv = Y4[lane * 64 + wl];
            float4 zv = Z4[lane * 64 + wl];
            float xs4[4] = {xv.x, xv.y, xv.z, xv.w};
            float ys4[4] = {yv.x, yv.y, yv.z, yv.w};
            float zs4[4] = {zv.x, zv.y, zv.z, zv.w};
            unsigned int p = (unsigned int)(lane * 256 + wl * 4);
            unsigned long long s0 = ~0ull, s1 = ~0ull, s2 = ~0ull, s3 = ~0ull;
#pragma unroll
            for (int u = 0; u < 4; ++u) {
                float dx = __fsub_rn(cx, xs4[u]);
                float dy = __fsub_rn(cy, ys4[u]);
                float dz = __fsub_rn(cz, zs4[u]);
                float d = __fadd_rn(__fadd_rn(__fmul_rn(dx, dx), __fmul_rn(dy, dy)),
                                    __fmul_rn(dz, dz));
                unsigned long long v =
                    ((unsigned long long)__float_as_uint(d) << 32) | (p + u);
                if ((mw >> (((lane & 15) << 2) | u)) & 1ull) v = ~0ull;
                ins4(s0, s1, s2, s3, v);
            }
            // butterfly merge of sorted quads -> global top-4 of remaining
#pragma unroll
            for (int m = 1; m < 64; m <<= 1) {
                unsigned long long o0 = __shfl_xor(s0, m, 64);
                unsigned long long o1 = __shfl_xor(s1, m, 64);
                unsigned long long o2 = __shfl_xor(s2, m, 64);
                unsigned long long o3 = __shfl_xor(s3, m, 64);
                ins4(s0, s1, s2, s3, o0);
                ins4(s0, s1, s2, s3, o1);
                ins4(s0, s1, s2, s3, o2);
                ins4(s0, s1, s2, s3, o3);
            }
            if (lane == wl) { c0 = s0; c1 = s1; c2 = s2; c3 = s3; cnt = 4; }
        }

        // exact global top-2 from each lane's best-2 remaining
        unsigned long long r1 = c0, r2 = c1;
#pragma unroll
        for (int m = 1; m < 64; m <<= 1) {
            unsigned long long o1 = __shfl_xor(r1, m, 64);
            unsigned long long o2 = __shfl_xor(r2, m, 64);
            merge2(r1, r2, o1, o2);
        }
        const int q1 = (int)(unsigned int)r1;
        const int q2 = (int)(unsigned int)r2;
        if (lane == 0) { knn_sh[wave][2 * r] = q1; knn_sh[wave][2 * r + 1] = q2; }

        // pops: owner's c0 == extracted key; shift cache, mark removed bit
        const int o1l = (q1 >> 2) & 63;
        if (lane == o1l) {
            const int sl = ((q1 >> 8) << 2) | (q1 & 3);
            unsigned long long bit = 1ull << (sl & 63);
            rm0 |= ((sl >> 6) == 0) ? bit : 0ull;
            rm1 |= ((sl >> 6) == 1) ? bit : 0ull;
            rm2 |= ((sl >> 6) == 2) ? bit : 0ull;
            rm3 |= ((sl >> 6) == 3) ? bit : 0ull;
            c0 = c1; c1 = c2; c2 = c3; c3 = ~0ull; --cnt;
        }
        const int o2l = (q2 >> 2) & 63;
        if (lane == o2l) {
            const int sl = ((q2 >> 8) << 2) | (q2 & 3);
            unsigned long long bit = 1ull << (sl & 63);
            rm0 |= ((sl >> 6) == 0) ? bit : 0ull;
            rm1 |= ((sl >> 6) == 1) ? bit : 0ull;
            rm2 |= ((sl >> 6) == 2) ? bit : 0ull;
            rm3 |= ((sl >> 6) == 3) ? bit : 0ull;
            c0 = c1; c1 = c2; c2 = c3; c3 = ~0ull; --cnt;
        }
    }
    __syncthreads();

    // gather 32 x 6, subtract center from xyz channels
#pragma unroll
    for (int t = 0; t < 3; ++t) {
        int i = lane + 64 * t;
        int k = i / 6, c = i % 6;
        int p = knn_sh[wave][k];
        float val = xb[c * N_PTS + p];
        if (c == 0) val = __fsub_rn(val, cx);
        else if (c == 1) val = __fsub_rn(val, cy);
        else if (c == 2) val = __fsub_rn(val, cz);
        xout[(size_t)bg_out * 192 + i] = val;
    }
}

// ---------------- Phase C: MLP v4 — M=64 half-block, 512 thr (frozen this round) ----------------
__global__ __launch_bounds__(512, 4) void mlp_mfma_kernel(
    const float* __restrict__ xin,
    const float* __restrict__ w1, const float* __restrict__ b1,
    const float* __restrict__ g1, const float* __restrict__ be1,
    const float* __restrict__ m1, const float* __restrict__ v1,
    const unsigned short* __restrict__ w2t, const float* __restrict__ b2,
    const unsigned short* __restrict__ w3t, const float* __restrict__ b3,
    const float* __restrict__ g2, const float* __restrict__ be2,
    const float* __restrict__ m2, const float* __restrict__ v2,
    const unsigned short* __restrict__ w4t, const float* __restrict__ b4,
    float* __restrict__ out) {
    const int g0 = blockIdx.x * 2;
    const int t = threadIdx.x;
    const int w = t >> 6;
    const int lane = t & 63;
    const int lr = lane & 15;
    const int lq = lane >> 4;

    __shared__ __align__(16) unsigned short f2s[64 * 264];
    __shared__ __align__(16) unsigned short ubuf[64 * 136];
    __shared__ __align__(16) unsigned short fgs[4 * 256];
    __shared__ float xs[2 * 192];

    unsigned short* f1s = ubuf;
    unsigned short* f3c = ubuf;

    if (t < 384) xs[t] = xin[(size_t)g0 * 192 + t];
    __syncthreads();

    {
        const int d = t & 127, rq = t >> 7;  // rq in [0,4): 16 rows each
        float wv[6];
#pragma unroll
        for (int c = 0; c < 6; ++c) wv[c] = w1[c * 128 + d];
        const float sc = g1[d] * rsqrtf(v1[d] + EPSF);
        const float sh = be1[d] - m1[d] * sc;
        const float bias = b1[d];

#pragma unroll
        for (int j = 0; j < 16; ++j) {
            const int rl = rq * 16 + j;          // row 0..63
            const int g = rl >> 5, k = rl & 31;
            float acc = bias;
#pragma unroll
            for (int c = 0; c < 6; ++c) acc += xs[g * 192 + k * 6 + c] * wv[c];
            f1s[rl * 136 + d] = f2bf(fmaxf(acc * sc + sh, 0.0f));
        }
        __syncthreads();

        // L2 MFMA: rows mtl*16, cols w*32 + nti*16
        f32x4 acc[4][2];
#pragma unroll
        for (int nti = 0; nti < 2; ++nti) {
            f32x4 bq = *(const f32x4*)(b2 + w * 32 + nti * 16 + lq * 4);
#pragma unroll
            for (int mtl = 0; mtl < 4; ++mtl) acc[mtl][nti] = bq;
        }
#pragma unroll
        for (int ks = 0; ks < 4; ++ks) {
            bf16x8 xf[4], wf[2];
#pragma unroll
            for (int mtl = 0; mtl < 4; ++mtl)
                xf[mtl] = *(const bf16x8*)(f1s + (mtl * 16 + lr) * 136 + ks * 32 + lq * 8);
#pragma unroll
            for (int nti = 0; nti < 2; ++nti)
                wf[nti] = *(const bf16x8*)(w2t + (w * 32 + nti * 16 + lr) * 128 + ks * 32 + lq * 8);
#pragma unroll
            for (int mtl = 0; mtl < 4; ++mtl)
#pragma unroll
                for (int nti = 0; nti < 2; ++nti)
                    acc[mtl][nti] = __builtin_amdgcn_mfma_f32_16x16x32_bf16(wf[nti], xf[mtl], acc[mtl][nti], 0, 0, 0);
        }
#pragma unroll
        for (int mtl = 0; mtl < 4; ++mtl)
#pragma unroll
            for (int nti = 0; nti < 2; ++nti) {
                bf16x4 p;
#pragma unroll
                for (int r = 0; r < 4; ++r) p[r] = (short)f2bf(acc[mtl][nti][r]);
                *(bf16x4*)(f2s + (size_t)(mtl * 16 + lr) * 264 + w * 32 + nti * 16 + lq * 4) = p;
            }
        __syncthreads();
    }

    {
        // group-max into fgs rows 0..1; zero rows 2..3 (accH safety)
        const int g = t >> 8, n = t & 255;   // 512 threads cover 2x256
        float m = -3.9e38f;
#pragma unroll
        for (int k = 0; k < 32; ++k) m = fmaxf(m, bf2f(f2s[(size_t)(g * 32 + k) * 264 + n]));
        fgs[g * 256 + n] = f2bf(m);
        fgs[512 + t] = 0;
    }
    __syncthreads();

    auto ldw3 = [&](int cb_, int ks_) -> bf16x8 {
        return *(const bf16x8*)(w3t + (size_t)(cb_ * 128 + w * 16 + lr) * 512 + ks_ * 32 + lq * 8);
    };
    auto ldw4 = [&](int cb_, int kl_, int nti_) -> bf16x8 {
        return *(const bf16x8*)(w4t + (size_t)(w * 48 + nti_ * 16 + lr) * 512 + cb_ * 128 + kl_ * 32 + lq * 8);
    };

    f32x4 acc4[3][4];
#pragma unroll
    for (int nti = 0; nti < 3; ++nti) {
        f32x4 bq = *(const f32x4*)(b4 + w * 48 + nti * 16 + lq * 4);
#pragma unroll
        for (int ml = 0; ml < 4; ++ml) acc4[nti][ml] = bq;
    }

    for (int cb = 0; cb < 4; ++cb) {
        bf16x8 wp[4];
#pragma unroll
        for (int kp = 0; kp < 4; ++kp) wp[kp] = ldw3(cb, kp);

        // fg-half GEMM
        f32x4 accH = *(const f32x4*)(b3 + cb * 128 + w * 16 + lq * 4);
#pragma unroll
        for (int ks = 0; ks < 8; ++ks) {
            bf16x8 wf = wp[ks & 3];
            wp[ks & 3] = ldw3(cb, ks + 4);
            bf16x8 xfh = *(const bf16x8*)(fgs + (lr & 3) * 256 + ks * 32 + lq * 8);
            accH = __builtin_amdgcn_mfma_f32_16x16x32_bf16(wf, xfh, accH, 0, 0, 0);
        }
        f32x4 acc3[4];
#pragma unroll
        for (int ml = 0; ml < 4; ++ml) {
            const int gg = ml >> 1;              // group of row-tile ml
#pragma unroll
            for (int r = 0; r < 4; ++r)
                acc3[ml][r] = __shfl(accH[r], (lane & 48) | gg, 64);
        }
#pragma unroll
        for (int ks = 8; ks < 16; ++ks) {
            bf16x8 wf = wp[ks & 3];
            if (ks + 4 < 16) wp[ks & 3] = ldw3(cb, ks + 4);
#pragma unroll
            for (int ml = 0; ml < 4; ++ml) {
                bf16x8 xf = *(const bf16x8*)(f2s + (size_t)(ml * 16 + lr) * 264 + (ks - 8) * 32 + lq * 8);
                acc3[ml] = __builtin_amdgcn_mfma_f32_16x16x32_bf16(wf, xf, acc3[ml], 0, 0, 0);
            }
        }
        {
            const int nq = cb * 128 + w * 16 + lq * 4;
            f32x4 g2q = *(const f32x4*)(g2 + nq);
            f32x4 v2q = *(const f32x4*)(v2 + nq);
            f32x4 m2q = *(const f32x4*)(m2 + nq);
            f32x4 beq = *(const f32x4*)(be2 + nq);
            f32x4 sc, sh;
#pragma unroll
            for (int r = 0; r < 4; ++r) {
                sc[r] = g2q[r] * rsqrtf(v2q[r] + EPSF);
                sh[r] = beq[r] - m2q[r] * sc[r];
            }
#pragma unroll
            for (int ml = 0; ml < 4; ++ml) {
                bf16x4 p;
#pragma unroll
                for (int r = 0; r < 4; ++r)
                    p[r] = (short)f2bf(fmaxf(acc3[ml][r] * sc[r] + sh[r], 0.0f));
                *(bf16x4*)(f3c + (size_t)(ml * 16 + lr) * 136 + w * 16 + lq * 4) = p;
            }
        }
        bf16x8 w4a[3];
#pragma unroll
        for (int nti = 0; nti < 3; ++nti) w4a[nti] = ldw4(cb, 0, nti);
        __syncthreads();
        for (int kl = 0; kl < 4; ++kl) {
            bf16x8 w4n[3];
            if (kl < 3) {
#pragma unroll
                for (int nti = 0; nti < 3; ++nti) w4n[nti] = ldw4(cb, kl + 1, nti);
            }
            bf16x8 xf8[4];
#pragma unroll
            for (int ml = 0; ml < 4; ++ml)
                xf8[ml] = *(const bf16x8*)(f3c + (size_t)(ml * 16 + lr) * 136 + kl * 32 + lq * 8);
#pragma unroll
            for (int nti = 0; nti < 3; ++nti)
#pragma unroll
                for (int ml = 0; ml < 4; ++ml)
                    acc4[nti][ml] = __builtin_amdgcn_mfma_f32_16x16x32_bf16(w4a[nti], xf8[ml], acc4[nti][ml], 0, 0, 0);
            if (kl < 3) {
#pragma unroll
                for (int nti = 0; nti < 3; ++nti) w4a[nti] = w4n[nti];
            }
        }
        __syncthreads();
    }

#pragma unroll
    for (int nti = 0; nti < 3; ++nti) {
#pragma unroll
        for (int gg = 0; gg < 2; ++gg) {
            f32x4 vv;
#pragma unroll
            for (int r = 0; r < 4; ++r)
                vv[r] = fmaxf(acc4[nti][2 * gg][r], acc4[nti][2 * gg + 1][r]);
#pragma unroll
            for (int mask = 1; mask <= 8; mask <<= 1) {
#pragma unroll
                for (int r = 0; r < 4; ++r)
                    vv[r] = fmaxf(vv[r], __shfl_xor(vv[r], mask, 64));
            }
            if (lr == 0)
                *(f32x4*)(out + (size_t)(g0 + gg) * 384 + w * 48 + nti * 16 + lq * 4) = vv;
        }
    }
}

extern "C" void kernel_launch(void* const* d_in, const int* in_sizes, int n_in,
                              void* d_out, int out_size, void* d_ws, size_t ws_size,
                              hipStream_t stream) {
    const float* pcd = (const float*)d_in[0];
    const float* w1 = (const float*)d_in[2];
    const float* b1 = (const float*)d_in[3];
    const float* g1 = (const float*)d_in[4];
    const float* be1 = (const float*)d_in[5];
    const float* m1 = (const float*)d_in[6];
    const float* v1 = (const float*)d_in[7];
    const float* w2 = (const float*)d_in[8];
    const float* b2 = (const float*)d_in[9];
    const float* w3 = (const float*)d_in[10];
    const float* b3 = (const float*)d_in[11];
    const float* g2 = (const float*)d_in[12];
    const float* be2 = (const float*)d_in[13];
    const float* m2 = (const float*)d_in[14];
    const float* v2 = (const float*)d_in[15];
    const float* w4 = (const float*)d_in[16];
    const float* b4 = (const float*)d_in[17];
    float* out = (float*)d_out;

    char* ws = (char*)d_ws;
    int* cidx = (int*)ws;                                   // 8192 B
    float* xg = (float*)(ws + 8192);                        // 1,572,864 B
    unsigned short* w2t = (unsigned short*)(ws + 1581056);  // 65,536 B
    unsigned short* w3t = (unsigned short*)(ws + 1646592);  // 524,288 B
    unsigned short* w4t = (unsigned short*)(ws + 2170880);  // 393,216 B

    fps_prep_kernel<<<152, 1024, 0, stream>>>(pcd, cidx, w2, w3, w4, w2t, w3t, w4t);
    knn_kernel<<<512, 256, 0, stream>>>(pcd, cidx, xg);
    mlp_mfma_kernel<<<1024, 512, 0, stream>>>(xg, w1, b1, g1, be1, m1, v1,
                                              w2t, b2, w3t, b3, g2, be2, m2, v2,
                                              w4t, b4, out);
}

// Round 7
// 358.261 us; speedup vs baseline: 1.1518x; 1.1017x over previous
//
#include <hip/hip_runtime.h>
#include <hip/hip_bf16.h>
#include <math.h>

#define N_PTS 16384
#define NUM_G 64
#define GRP_K 32
#define EPSF 1e-5f

typedef short bf16x8 __attribute__((ext_vector_type(8)));
typedef short bf16x4 __attribute__((ext_vector_type(4)));
typedef float f32x4 __attribute__((ext_vector_type(4)));
typedef unsigned short u16x8 __attribute__((ext_vector_type(8)));

__device__ __forceinline__ unsigned short f2bf(float x) {
    unsigned int u = __builtin_bit_cast(unsigned int, x);
    u = (u + 0x7FFFu + ((u >> 16) & 1u)) >> 16;
    return (unsigned short)u;
}
__device__ __forceinline__ float bf2f(unsigned short h) {
    unsigned int u = ((unsigned int)h) << 16;
    return __builtin_bit_cast(float, u);
}

// ---------------- Fused Phase A: FPS v5 (frozen — structural floor ~126us) + weight prep ----------------
__global__ __launch_bounds__(1024)
__attribute__((amdgpu_waves_per_eu(4, 4)))
void fps_prep_kernel(const float* __restrict__ pcd, int* __restrict__ cidx,
                     const float* __restrict__ w2, const float* __restrict__ w3,
                     const float* __restrict__ w4,
                     unsigned short* __restrict__ w2t,
                     unsigned short* __restrict__ w3t,
                     unsigned short* __restrict__ w4t) {
    __shared__ unsigned long long wk[2][16];
    __shared__ int clds[NUM_G];
    __shared__ unsigned short tl[64][72];

    const int tid = threadIdx.x;

    if (blockIdx.x >= 32) {
        if (tid < 256) {
            const int tile = blockIdx.x - 32;
            const float* src;
            unsigned short* dst;
            int K, N, kt, nt;
            if (tile < 8) {
                src = w2; dst = w2t; K = 128; N = 256;
                kt = tile >> 2; nt = tile & 3;
            } else if (tile < 72) {
                int t2 = tile - 8;
                src = w3; dst = w3t; K = 512; N = 512;
                kt = t2 >> 3; nt = t2 & 7;
            } else {
                int t2 = tile - 72;
                src = w4; dst = w4t; K = 512; N = 384;
                kt = t2 / 6; nt = t2 % 6;
            }
            const int k0 = kt * 64, n0 = nt * 64;
            const int c = tid & 63, r0 = tid >> 6;
#pragma unroll
            for (int i = 0; i < 16; ++i) {
                int r = 4 * i + r0;
                tl[r][c] = f2bf(src[(size_t)(k0 + r) * N + n0 + c]);
            }
            __syncthreads();
            const int n = tid >> 2;
            const int kc = (tid & 3) * 16;
            u16x8 v0, v1;
#pragma unroll
            for (int j = 0; j < 8; ++j) {
                v0[j] = tl[kc + j][n];
                v1[j] = tl[kc + 8 + j][n];
            }
            *(u16x8*)(dst + (size_t)(n0 + n) * K + k0 + kc) = v0;
            *(u16x8*)(dst + (size_t)(n0 + n) * K + k0 + kc + 8) = v1;
        } else {
            __syncthreads();
        }
        return;
    }

    const int b = blockIdx.x;
    const int lane = tid & 63, w = tid >> 6;
    const float* xb = pcd + (size_t)b * 6 * N_PTS;
    const float4* Xc = (const float4*)xb;
    const float4* Yc = (const float4*)(xb + N_PTS);
    const float4* Zc = (const float4*)(xb + 2 * N_PTS);

    float dist[16];
#pragma unroll
    for (int j = 0; j < 16; ++j) dist[j] = 1e10f;

    int far = 0;
    for (int it = 0; it < NUM_G; ++it) {
        int fu = __builtin_amdgcn_readfirstlane(far);
        float cx = xb[fu], cy = xb[N_PTS + fu], cz = xb[2 * N_PTS + fu];
        if (tid == 0) clds[it] = fu;

        float bv = -1.0f;
        int bj = 0;
#pragma unroll
        for (int jp = 0; jp < 4; ++jp) {
            float4 xq = Xc[tid * 4 + jp];
            float4 yq = Yc[tid * 4 + jp];
            float4 zq = Zc[tid * 4 + jp];
            float xa[4] = {xq.x, xq.y, xq.z, xq.w};
            float ya[4] = {yq.x, yq.y, yq.z, yq.w};
            float za[4] = {zq.x, zq.y, zq.z, zq.w};
#pragma unroll
            for (int u = 0; u < 4; ++u) {
                const int j = jp * 4 + u;
                float dx = __fsub_rn(xa[u], cx);
                float dy = __fsub_rn(ya[u], cy);
                float dz = __fsub_rn(za[u], cz);
                float d = __fadd_rn(__fadd_rn(__fmul_rn(dx, dx), __fmul_rn(dy, dy)),
                                    __fmul_rn(dz, dz));
                dist[j] = fminf(dist[j], d);
                if (dist[j] > bv) { bv = dist[j]; bj = j; }
            }
        }
        float vmax = bv;
#pragma unroll
        for (int m = 1; m < 64; m <<= 1) {
            float o = __shfl_xor(vmax, m, 64);
            vmax = o > vmax ? o : vmax;
        }
        unsigned long long mk = __ballot(bv == vmax);
        int fl = __ffsll((unsigned long long)mk) - 1;
        int bjw = __shfl(bj, fl, 64);
        int idx = (((w << 6) | fl) << 4) + bjw;
        unsigned long long key =
            ((unsigned long long)__float_as_uint(vmax) << 32) | (unsigned int)~idx;
        if (lane == 0) wk[it & 1][w] = key;
        __syncthreads();
        unsigned long long k2 = (lane < 16) ? wk[it & 1][lane] : 0ull;
#pragma unroll
        for (int m = 1; m < 16; m <<= 1) {
            unsigned long long o = __shfl_xor(k2, m, 64);
            k2 = o > k2 ? o : k2;
        }
        k2 = __shfl(k2, 0, 64);
        far = (int)(~(unsigned int)k2);
    }
    __syncthreads();
    if (tid < NUM_G) cidx[b * NUM_G + tid] = clds[tid];
}

// ---------------- Phase B: KNN v4 — 4 groups per 256-thr workgroup (frozen this round) ----------------
__device__ __forceinline__ void merge2(unsigned long long& a1, unsigned long long& a2,
                                       unsigned long long o1, unsigned long long o2) {
    unsigned long long hi = a1 > o1 ? a1 : o1;
    a1 = a1 < o1 ? a1 : o1;
    unsigned long long lo2 = a2 < o2 ? a2 : o2;
    a2 = hi < lo2 ? hi : lo2;
}
// sorted ascending insert of v into (c0<=c1<=c2<=c3), keeping 4 smallest
__device__ __forceinline__ void ins4(unsigned long long& c0, unsigned long long& c1,
                                     unsigned long long& c2, unsigned long long& c3,
                                     unsigned long long v) {
    if (v < c3) {
        unsigned long long t3 = c2 > v ? c2 : v;
        unsigned long long t2 = c2 > v ? v : c2;
        unsigned long long u2 = c1 > t2 ? c1 : t2;
        unsigned long long u1 = c1 > t2 ? t2 : c1;
        unsigned long long s1 = c0 > u1 ? c0 : u1;
        unsigned long long s0 = c0 > u1 ? u1 : c0;
        c0 = s0; c1 = s1; c2 = u2; c3 = t3;
    }
}

__global__ __launch_bounds__(256)
void knn_kernel(const float* __restrict__ pcd,
                const int* __restrict__ cidx,
                float* __restrict__ xout) {
    const int b = blockIdx.x & 31;             // XCD-locality swizzle
    const int wave = threadIdx.x >> 6;
    const int g = (blockIdx.x >> 5) * 4 + wave;
    const int bg_out = b * NUM_G + g;
    const int lane = threadIdx.x & 63;
    const float* xb = pcd + (size_t)b * 6 * N_PTS;

    const int ci = cidx[bg_out];
    const float cx = xb[ci], cy = xb[N_PTS + ci], cz = xb[2 * N_PTS + ci];

    const float4* X4 = (const float4*)xb;
    const float4* Y4 = (const float4*)(xb + N_PTS);
    const float4* Z4 = (const float4*)(xb + 2 * N_PTS);

    // per-lane sorted top-4 cache of its 256 points p = j*256 + lane*4 + u
    unsigned long long c0 = ~0ull, c1 = ~0ull, c2 = ~0ull, c3 = ~0ull;
#pragma unroll 8
    for (int j = 0; j < 64; ++j) {
        float4 xv = X4[j * 64 + lane];
        float4 yv = Y4[j * 64 + lane];
        float4 zv = Z4[j * 64 + lane];
        float xs4[4] = {xv.x, xv.y, xv.z, xv.w};
        float ys4[4] = {yv.x, yv.y, yv.z, yv.w};
        float zs4[4] = {zv.x, zv.y, zv.z, zv.w};
        unsigned int p = (unsigned int)(j * 256 + lane * 4);
#pragma unroll
        for (int u = 0; u < 4; ++u) {
            float dx = __fsub_rn(cx, xs4[u]);
            float dy = __fsub_rn(cy, ys4[u]);
            float dz = __fsub_rn(cz, zs4[u]);
            float d = __fadd_rn(__fadd_rn(__fmul_rn(dx, dx), __fmul_rn(dy, dy)),
                                __fmul_rn(dz, dz));
            ins4(c0, c1, c2, c3, ((unsigned long long)__float_as_uint(d) << 32) | (p + u));
        }
    }
    int cnt = 4;

    unsigned long long rm0 = 0, rm1 = 0, rm2 = 0, rm3 = 0;
    __shared__ int knn_sh[4][GRP_K];

    for (int r = 0; r < 16; ++r) {
        // refill any lane whose cache dropped below 2 valid (rare)
        while (true) {
            unsigned long long need = __ballot(cnt < 2);
            if (need == 0ull) break;
            const int wl = __ffsll(need) - 1;
            unsigned long long m0 = __shfl(rm0, wl, 64);
            unsigned long long m1 = __shfl(rm1, wl, 64);
            unsigned long long m2 = __shfl(rm2, wl, 64);
            unsigned long long m3 = __shfl(rm3, wl, 64);
            const int wsel = lane >> 4;
            unsigned long long mw = wsel == 0 ? m0 : (wsel == 1 ? m1 : (wsel == 2 ? m2 : m3));
            // lane covers owner wl's 4 points at j=lane: p = lane*256 + wl*4 + u
            float4 xv = X4[lane * 64 + wl];
            float4 yv = Y4[lane * 64 + wl];
            float4 zv = Z4[lane * 64 + wl];
            float xs4[4] = {xv.x, xv.y, xv.z, xv.w};
            float ys4[4] = {yv.x, yv.y, yv.z, yv.w};
            float zs4[4] = {zv.x, zv.y, zv.z, zv.w};
            unsigned int p = (unsigned int)(lane * 256 + wl * 4);
            unsigned long long s0 = ~0ull, s1 = ~0ull, s2 = ~0ull, s3 = ~0ull;
#pragma unroll
            for (int u = 0; u < 4; ++u) {
                float dx = __fsub_rn(cx, xs4[u]);
                float dy = __fsub_rn(cy, ys4[u]);
                float dz = __fsub_rn(cz, zs4[u]);
                float d = __fadd_rn(__fadd_rn(__fmul_rn(dx, dx), __fmul_rn(dy, dy)),
                                    __fmul_rn(dz, dz));
                unsigned long long v =
                    ((unsigned long long)__float_as_uint(d) << 32) | (p + u);
                if ((mw >> (((lane & 15) << 2) | u)) & 1ull) v = ~0ull;
                ins4(s0, s1, s2, s3, v);
            }
            // butterfly merge of sorted quads -> global top-4 of remaining
#pragma unroll
            for (int m = 1; m < 64; m <<= 1) {
                unsigned long long o0 = __shfl_xor(s0, m, 64);
                unsigned long long o1 = __shfl_xor(s1, m, 64);
                unsigned long long o2 = __shfl_xor(s2, m, 64);
                unsigned long long o3 = __shfl_xor(s3, m, 64);
                ins4(s0, s1, s2, s3, o0);
                ins4(s0, s1, s2, s3, o1);
                ins4(s0, s1, s2, s3, o2);
                ins4(s0, s1, s2, s3, o3);
            }
            if (lane == wl) { c0 = s0; c1 = s1; c2 = s2; c3 = s3; cnt = 4; }
        }

        // exact global top-2 from each lane's best-2 remaining
        unsigned long long r1 = c0, r2 = c1;
#pragma unroll
        for (int m = 1; m < 64; m <<= 1) {
            unsigned long long o1 = __shfl_xor(r1, m, 64);
            unsigned long long o2 = __shfl_xor(r2, m, 64);
            merge2(r1, r2, o1, o2);
        }
        const int q1 = (int)(unsigned int)r1;
        const int q2 = (int)(unsigned int)r2;
        if (lane == 0) { knn_sh[wave][2 * r] = q1; knn_sh[wave][2 * r + 1] = q2; }

        // pops: owner's c0 == extracted key; shift cache, mark removed bit
        const int o1l = (q1 >> 2) & 63;
        if (lane == o1l) {
            const int sl = ((q1 >> 8) << 2) | (q1 & 3);
            unsigned long long bit = 1ull << (sl & 63);
            rm0 |= ((sl >> 6) == 0) ? bit : 0ull;
            rm1 |= ((sl >> 6) == 1) ? bit : 0ull;
            rm2 |= ((sl >> 6) == 2) ? bit : 0ull;
            rm3 |= ((sl >> 6) == 3) ? bit : 0ull;
            c0 = c1; c1 = c2; c2 = c3; c3 = ~0ull; --cnt;
        }
        const int o2l = (q2 >> 2) & 63;
        if (lane == o2l) {
            const int sl = ((q2 >> 8) << 2) | (q2 & 3);
            unsigned long long bit = 1ull << (sl & 63);
            rm0 |= ((sl >> 6) == 0) ? bit : 0ull;
            rm1 |= ((sl >> 6) == 1) ? bit : 0ull;
            rm2 |= ((sl >> 6) == 2) ? bit : 0ull;
            rm3 |= ((sl >> 6) == 3) ? bit : 0ull;
            c0 = c1; c1 = c2; c2 = c3; c3 = ~0ull; --cnt;
        }
    }
    __syncthreads();

    // gather 32 x 6, subtract center from xyz channels
#pragma unroll
    for (int t = 0; t < 3; ++t) {
        int i = lane + 64 * t;
        int k = i / 6, c = i % 6;
        int p = knn_sh[wave][k];
        float val = xb[c * N_PTS + p];
        if (c == 0) val = __fsub_rn(val, cx);
        else if (c == 1) val = __fsub_rn(val, cy);
        else if (c == 2) val = __fsub_rn(val, cz);
        xout[(size_t)bg_out * 192 + i] = val;
    }
}

// ---------------- Phase C: M=128 mega-block MFMA MLP (v2 — REVERTED, measured ~99us) ----------------
// R4/R5 attribution redo: mlp_v2 ~= 99us (369.7 - 127 fps - 144 knn_v3),
// so the v3 (141.5) and v4 (136.6) rewrites were regressions. Restore v2
// byte-for-byte. Do not touch without counter evidence.
__global__ __launch_bounds__(512, 2) void mlp_mfma_kernel(
    const float* __restrict__ xin,
    const float* __restrict__ w1, const float* __restrict__ b1,
    const float* __restrict__ g1, const float* __restrict__ be1,
    const float* __restrict__ m1, const float* __restrict__ v1,
    const unsigned short* __restrict__ w2t, const float* __restrict__ b2,
    const unsigned short* __restrict__ w3t, const float* __restrict__ b3,
    const float* __restrict__ g2, const float* __restrict__ be2,
    const float* __restrict__ m2, const float* __restrict__ v2,
    const unsigned short* __restrict__ w4t, const float* __restrict__ b4,
    float* __restrict__ out) {
    const int g0 = blockIdx.x * 4;
    const int t = threadIdx.x;
    const int w = t >> 6;
    const int lane = t & 63;
    const int lr = lane & 15;
    const int lq = lane >> 4;

    __shared__ __align__(16) unsigned short f2s[128 * 264];
    __shared__ __align__(16) unsigned short ubuf[128 * 136];
    __shared__ __align__(16) unsigned short fgs[4 * 256];
    __shared__ float xs[4 * 192];

    unsigned short* f1s = ubuf;
    unsigned short* f3c = ubuf;

    for (int i = t; i < 768; i += 512) xs[i] = xin[(size_t)g0 * 192 + i];
    __syncthreads();

    {
        const int d = t & 127, rq = t >> 7;
        float wv[6];
#pragma unroll
        for (int c = 0; c < 6; ++c) wv[c] = w1[c * 128 + d];
        const float sc = g1[d] * rsqrtf(v1[d] + EPSF);
        const float sh = be1[d] - m1[d] * sc;
        const float bias = b1[d];

        for (int s = 0; s < 2; ++s) {
#pragma unroll
            for (int j = 0; j < 16; ++j) {
                const int rl = rq * 16 + j;
                const int gr = s * 64 + rl;
                const int g = gr >> 5, k = gr & 31;
                float acc = bias;
#pragma unroll
                for (int c = 0; c < 6; ++c) acc += xs[g * 192 + k * 6 + c] * wv[c];
                f1s[rl * 136 + d] = f2bf(fmaxf(acc * sc + sh, 0.0f));
            }
            __syncthreads();
            f32x4 acc[4][2];
#pragma unroll
            for (int nti = 0; nti < 2; ++nti) {
                f32x4 bq = *(const f32x4*)(b2 + w * 32 + nti * 16 + lq * 4);
#pragma unroll
                for (int mtl = 0; mtl < 4; ++mtl) acc[mtl][nti] = bq;
            }
#pragma unroll
            for (int ks = 0; ks < 4; ++ks) {
                bf16x8 xf[4], wf[2];
#pragma unroll
                for (int mtl = 0; mtl < 4; ++mtl)
                    xf[mtl] = *(const bf16x8*)(f1s + (mtl * 16 + lr) * 136 + ks * 32 + lq * 8);
#pragma unroll
                for (int nti = 0; nti < 2; ++nti)
                    wf[nti] = *(const bf16x8*)(w2t + (w * 32 + nti * 16 + lr) * 128 + ks * 32 + lq * 8);
#pragma unroll
                for (int mtl = 0; mtl < 4; ++mtl)
#pragma unroll
                    for (int nti = 0; nti < 2; ++nti)
                        acc[mtl][nti] = __builtin_amdgcn_mfma_f32_16x16x32_bf16(wf[nti], xf[mtl], acc[mtl][nti], 0, 0, 0);
            }
#pragma unroll
            for (int mtl = 0; mtl < 4; ++mtl)
#pragma unroll
                for (int nti = 0; nti < 2; ++nti) {
                    bf16x4 p;
#pragma unroll
                    for (int r = 0; r < 4; ++r) p[r] = (short)f2bf(acc[mtl][nti][r]);
                    *(bf16x4*)(f2s + (size_t)(s * 64 + mtl * 16 + lr) * 264 + w * 32 + nti * 16 + lq * 4) = p;
                }
            __syncthreads();
        }
    }

    for (int idx = t; idx < 1024; idx += 512) {
        int g = idx >> 8, n = idx & 255;
        float m = -3.9e38f;
#pragma unroll
        for (int k = 0; k < 32; ++k) m = fmaxf(m, bf2f(f2s[(size_t)(g * 32 + k) * 264 + n]));
        fgs[g * 256 + n] = f2bf(m);
    }
    __syncthreads();

    auto ldw3 = [&](int cb_, int ks_) -> bf16x8 {
        return *(const bf16x8*)(w3t + (size_t)(cb_ * 128 + w * 16 + lr) * 512 + ks_ * 32 + lq * 8);
    };
    auto ldw4 = [&](int cb_, int kl_, int nti_) -> bf16x8 {
        return *(const bf16x8*)(w4t + (size_t)(w * 48 + nti_ * 16 + lr) * 512 + cb_ * 128 + kl_ * 32 + lq * 8);
    };

    f32x4 acc4[3][8];
#pragma unroll
    for (int nti = 0; nti < 3; ++nti) {
        f32x4 bq = *(const f32x4*)(b4 + w * 48 + nti * 16 + lq * 4);
#pragma unroll
        for (int mt = 0; mt < 8; ++mt) acc4[nti][mt] = bq;
    }

    for (int cb = 0; cb < 4; ++cb) {
        bf16x8 wp[4];
#pragma unroll
        for (int kp = 0; kp < 4; ++kp) wp[kp] = ldw3(cb, kp);

        f32x4 accH = *(const f32x4*)(b3 + cb * 128 + w * 16 + lq * 4);
#pragma unroll
        for (int ks = 0; ks < 8; ++ks) {
            bf16x8 wf = wp[ks & 3];
            wp[ks & 3] = ldw3(cb, ks + 4);
            bf16x8 xfh = *(const bf16x8*)(fgs + (lr & 3) * 256 + ks * 32 + lq * 8);
            accH = __builtin_amdgcn_mfma_f32_16x16x32_bf16(wf, xfh, accH, 0, 0, 0);
        }
        f32x4 acc3[8];
#pragma unroll
        for (int mt = 0; mt < 8; ++mt) {
            const int gg = mt >> 1;
#pragma unroll
            for (int r = 0; r < 4; ++r)
                acc3[mt][r] = __shfl(accH[r], (lane & 48) | gg, 64);
        }
#pragma unroll
        for (int ks = 8; ks < 16; ++ks) {
            bf16x8 wf = wp[ks & 3];
            if (ks + 4 < 16) wp[ks & 3] = ldw3(cb, ks + 4);
#pragma unroll
            for (int mt = 0; mt < 8; ++mt) {
                bf16x8 xf = *(const bf16x8*)(f2s + (size_t)(mt * 16 + lr) * 264 + (ks - 8) * 32 + lq * 8);
                acc3[mt] = __builtin_amdgcn_mfma_f32_16x16x32_bf16(wf, xf, acc3[mt], 0, 0, 0);
            }
        }
        {
            const int nq = cb * 128 + w * 16 + lq * 4;
            f32x4 g2q = *(const f32x4*)(g2 + nq);
            f32x4 v2q = *(const f32x4*)(v2 + nq);
            f32x4 m2q = *(const f32x4*)(m2 + nq);
            f32x4 beq = *(const f32x4*)(be2 + nq);
            f32x4 sc, sh;
#pragma unroll
            for (int r = 0; r < 4; ++r) {
                sc[r] = g2q[r] * rsqrtf(v2q[r] + EPSF);
                sh[r] = beq[r] - m2q[r] * sc[r];
            }
#pragma unroll
            for (int mt = 0; mt < 8; ++mt) {
                bf16x4 p;
#pragma unroll
                for (int r = 0; r < 4; ++r)
                    p[r] = (short)f2bf(fmaxf(acc3[mt][r] * sc[r] + sh[r], 0.0f));
                *(bf16x4*)(f3c + (size_t)(mt * 16 + lr) * 136 + w * 16 + lq * 4) = p;
            }
        }
        bf16x8 w4a[3];
#pragma unroll
        for (int nti = 0; nti < 3; ++nti) w4a[nti] = ldw4(cb, 0, nti);
        __syncthreads();
        for (int kl = 0; kl < 4; ++kl) {
            bf16x8 w4n[3];
            if (kl < 3) {
#pragma unroll
                for (int nti = 0; nti < 3; ++nti) w4n[nti] = ldw4(cb, kl + 1, nti);
            }
            bf16x8 xf8[8];
#pragma unroll
            for (int mt = 0; mt < 8; ++mt)
                xf8[mt] = *(const bf16x8*)(f3c + (size_t)(mt * 16 + lr) * 136 + kl * 32 + lq * 8);
#pragma unroll
            for (int nti = 0; nti < 3; ++nti)
#pragma unroll
                for (int mt = 0; mt < 8; ++mt)
                    acc4[nti][mt] = __builtin_amdgcn_mfma_f32_16x16x32_bf16(w4a[nti], xf8[mt], acc4[nti][mt], 0, 0, 0);
            if (kl < 3) {
#pragma unroll
                for (int nti = 0; nti < 3; ++nti) w4a[nti] = w4n[nti];
            }
        }
        __syncthreads();
    }

#pragma unroll
    for (int nti = 0; nti < 3; ++nti) {
#pragma unroll
        for (int gg = 0; gg < 4; ++gg) {
            f32x4 vv;
#pragma unroll
            for (int r = 0; r < 4; ++r)
                vv[r] = fmaxf(acc4[nti][2 * gg][r], acc4[nti][2 * gg + 1][r]);
#pragma unroll
            for (int mask = 1; mask <= 8; mask <<= 1) {
#pragma unroll
                for (int r = 0; r < 4; ++r)
                    vv[r] = fmaxf(vv[r], __shfl_xor(vv[r], mask, 64));
            }
            if (lr == 0)
                *(f32x4*)(out + (size_t)(g0 + gg) * 384 + w * 48 + nti * 16 + lq * 4) = vv;
        }
    }
}

extern "C" void kernel_launch(void* const* d_in, const int* in_sizes, int n_in,
                              void* d_out, int out_size, void* d_ws, size_t ws_size,
                              hipStream_t stream) {
    const float* pcd = (const float*)d_in[0];
    const float* w1 = (const float*)d_in[2];
    const float* b1 = (const float*)d_in[3];
    const float* g1 = (const float*)d_in[4];
    const float* be1 = (const float*)d_in[5];
    const float* m1 = (const float*)d_in[6];
    const float* v1 = (const float*)d_in[7];
    const float* w2 = (const float*)d_in[8];
    const float* b2 = (const float*)d_in[9];
    const float* w3 = (const float*)d_in[10];
    const float* b3 = (const float*)d_in[11];
    const float* g2 = (const float*)d_in[12];
    const float* be2 = (const float*)d_in[13];
    const float* m2 = (const float*)d_in[14];
    const float* v2 = (const float*)d_in[15];
    const float* w4 = (const float*)d_in[16];
    const float* b4 = (const float*)d_in[17];
    float* out = (float*)d_out;

    char* ws = (char*)d_ws;
    int* cidx = (int*)ws;                                   // 8192 B
    float* xg = (float*)(ws + 8192);                        // 1,572,864 B
    unsigned short* w2t = (unsigned short*)(ws + 1581056);  // 65,536 B
    unsigned short* w3t = (unsigned short*)(ws + 1646592);  // 524,288 B
    unsigned short* w4t = (unsigned short*)(ws + 2170880);  // 393,216 B

    fps_prep_kernel<<<152, 1024, 0, stream>>>(pcd, cidx, w2, w3, w4, w2t, w3t, w4t);
    knn_kernel<<<512, 256, 0, stream>>>(pcd, cidx, xg);
    mlp_mfma_kernel<<<512, 512, 0, stream>>>(xg, w1, b1, g1, be1, m1, v1,
                                             w2t, b2, w3t, b3, g2, be2, m2, v2,
                                             w4t, b4, out);
}